// Round 6
// baseline (377.950 us; speedup 1.0000x reference)
//
#include <hip/hip_runtime.h>
#include <hip/hip_bf16.h>
#include <math.h>

#define T_LEN 4096
#define C_DIM 768
#define H_NUM 12
#define D_DIM 64

typedef __bf16 bf16x8 __attribute__((ext_vector_type(8)));
typedef float f32x16 __attribute__((ext_vector_type(16)));

static __device__ __forceinline__ unsigned short bf16bits(float f) {
    return __builtin_bit_cast(unsigned short, __float2bfloat16(f));
}

// ---------------------------------------------------------------------------
// Prep: Vt[h][d][t] = bf16(x[t][h*64+d]); if WX also xhi/xlo bf16 split of x.
// ---------------------------------------------------------------------------
template <bool WX>
__global__ __launch_bounds__(256) void vtx_kernel(
    const float* __restrict__ x,
    __hip_bfloat16* __restrict__ Vt,
    __hip_bfloat16* __restrict__ xhi,
    __hip_bfloat16* __restrict__ xlo) {
    __shared__ float tile[64][65];
    const int t0 = blockIdx.x * 64;
    const int c0 = blockIdx.y * 64;
    const int tid = threadIdx.x;
    const int cl = tid & 63;
    const int rq = tid >> 6;
#pragma unroll
    for (int rr = 0; rr < 16; ++rr) {
        const int row = rr * 4 + rq;
        const float v = x[(size_t)(t0 + row) * C_DIM + c0 + cl];
        tile[row][cl] = v;
        if (WX) {
            const __hip_bfloat16 hb = __float2bfloat16(v);
            xhi[(size_t)(t0 + row) * C_DIM + c0 + cl] = hb;
            xlo[(size_t)(t0 + row) * C_DIM + c0 + cl] =
                __float2bfloat16(v - __bfloat162float(hb));
        }
    }
    __syncthreads();
#pragma unroll
    for (int cc = 0; cc < 16; ++cc) {
        const int c = cc * 4 + rq;
        const int gc = c0 + c;
        const int h = gc >> 6, d = gc & 63;
        Vt[((size_t)h * D_DIM + d) * T_LEN + t0 + cl] =
            __float2bfloat16(tile[cl][c]);
    }
}

// ---------------------------------------------------------------------------
// Prep: Wt[w][n][k] = bf16(W_w[k][n]).  64x64 LDS transpose tiles.
// ---------------------------------------------------------------------------
__global__ __launch_bounds__(256) void wt_kernel(
    const float* __restrict__ Wk, const float* __restrict__ Wq,
    __hip_bfloat16* __restrict__ wt) {
    const float* W = blockIdx.z ? Wq : Wk;
    __hip_bfloat16* o = wt + (size_t)blockIdx.z * C_DIM * C_DIM;
    __shared__ float tile[64][65];
    const int k0 = blockIdx.x * 64;
    const int n0 = blockIdx.y * 64;
    const int tid = threadIdx.x;
    const int cl = tid & 63;
    const int rq = tid >> 6;
#pragma unroll
    for (int rr = 0; rr < 16; ++rr) {
        const int row = rr * 4 + rq;
        tile[row][cl] = W[(size_t)(k0 + row) * C_DIM + n0 + cl];
    }
    __syncthreads();
#pragma unroll
    for (int rr = 0; rr < 16; ++rr) {
        const int row = rr * 4 + rq;   // n within tile
        o[(size_t)(n0 + row) * C_DIM + k0 + cl] =
            __float2bfloat16(tile[cl][row]);
    }
}

// ---------------------------------------------------------------------------
// Projection via bf16 MFMA, split-x error compensation:
//   out = (xhi + xlo) @ W + b, fp32 accumulate, bf16 store [H][T][64].
// One wave = 64x64 tile. 1536 waves, 384 blocks, XCD chunk swizzle.
// ---------------------------------------------------------------------------
__global__ __launch_bounds__(256) void proj_mfma(
    const __hip_bfloat16* __restrict__ xhi,
    const __hip_bfloat16* __restrict__ xlo,
    const __hip_bfloat16* __restrict__ wt,
    const float* __restrict__ bk, const float* __restrict__ bq,
    __hip_bfloat16* __restrict__ kout, __hip_bfloat16* __restrict__ qout) {

    const int bid = blockIdx.x;                  // 384 blocks
    const int wg = (bid & 7) * 48 + (bid >> 3);  // 8 XCD chunks of 48
    const int u  = wg * 4 + (threadIdx.x >> 6);  // 0..1535
    const int mt = u / 24;
    const int r24 = u - mt * 24;
    const int wsel = r24 / 12;
    const int nt = r24 - wsel * 12;
    const int m0 = mt * 64, n0 = nt * 64;
    const int lane = threadIdx.x & 63;
    const int lm = lane & 31, hi = lane >> 5;

    const __hip_bfloat16* wb = wt + (size_t)wsel * C_DIM * C_DIM;
    const __hip_bfloat16* a0p = xhi + (size_t)(m0 + lm) * C_DIM + hi * 8;
    const __hip_bfloat16* a1p = a0p + 32 * C_DIM;
    const __hip_bfloat16* l0p = xlo + (size_t)(m0 + lm) * C_DIM + hi * 8;
    const __hip_bfloat16* l1p = l0p + 32 * C_DIM;
    const __hip_bfloat16* b0p = wb + (size_t)(n0 + lm) * C_DIM + hi * 8;
    const __hip_bfloat16* b1p = b0p + 32 * C_DIM;

    f32x16 acc00 = {}, acc01 = {}, acc10 = {}, acc11 = {};

#pragma unroll 4
    for (int k0 = 0; k0 < C_DIM; k0 += 16) {
        const bf16x8 a0 = *reinterpret_cast<const bf16x8*>(a0p + k0);
        const bf16x8 a1 = *reinterpret_cast<const bf16x8*>(a1p + k0);
        const bf16x8 b0 = *reinterpret_cast<const bf16x8*>(b0p + k0);
        const bf16x8 b1 = *reinterpret_cast<const bf16x8*>(b1p + k0);
        acc00 = __builtin_amdgcn_mfma_f32_32x32x16_bf16(a0, b0, acc00, 0, 0, 0);
        acc01 = __builtin_amdgcn_mfma_f32_32x32x16_bf16(a0, b1, acc01, 0, 0, 0);
        acc10 = __builtin_amdgcn_mfma_f32_32x32x16_bf16(a1, b0, acc10, 0, 0, 0);
        acc11 = __builtin_amdgcn_mfma_f32_32x32x16_bf16(a1, b1, acc11, 0, 0, 0);
        const bf16x8 l0 = *reinterpret_cast<const bf16x8*>(l0p + k0);
        const bf16x8 l1 = *reinterpret_cast<const bf16x8*>(l1p + k0);
        acc00 = __builtin_amdgcn_mfma_f32_32x32x16_bf16(l0, b0, acc00, 0, 0, 0);
        acc01 = __builtin_amdgcn_mfma_f32_32x32x16_bf16(l0, b1, acc01, 0, 0, 0);
        acc10 = __builtin_amdgcn_mfma_f32_32x32x16_bf16(l1, b0, acc10, 0, 0, 0);
        acc11 = __builtin_amdgcn_mfma_f32_32x32x16_bf16(l1, b1, acc11, 0, 0, 0);
    }

    const float* bias = wsel ? bq : bk;
    __hip_bfloat16* out = wsel ? qout : kout;
    const int h = nt;
    const float bv0 = bias[n0 + lm];
    const float bv1 = bias[n0 + 32 + lm];
#pragma unroll
    for (int r = 0; r < 16; ++r) {
        const int cr = (r & 3) + 8 * (r >> 2) + 4 * hi;
        const int t0r = m0 + cr;
        const int t1r = m0 + 32 + cr;
        out[((size_t)h * T_LEN + t0r) * D_DIM + lm]      = __float2bfloat16(acc00[r] + bv0);
        out[((size_t)h * T_LEN + t0r) * D_DIM + 32 + lm] = __float2bfloat16(acc01[r] + bv1);
        out[((size_t)h * T_LEN + t1r) * D_DIM + lm]      = __float2bfloat16(acc10[r] + bv0);
        out[((size_t)h * T_LEN + t1r) * D_DIM + 32 + lm] = __float2bfloat16(acc11[r] + bv1);
    }
}

// ---------------------------------------------------------------------------
// Fallback projection (Round-3 validated): fp32 compute, bf16 out [H][T][64].
// ---------------------------------------------------------------------------
__global__ __launch_bounds__(256) void proj_gemm(
    const float* __restrict__ x,
    const float* __restrict__ Wk, const float* __restrict__ bk,
    const float* __restrict__ Wq, const float* __restrict__ bq,
    __hip_bfloat16* __restrict__ kout, __hip_bfloat16* __restrict__ qout) {

    const float* W;
    const float* bias;
    __hip_bfloat16* out;
    if (blockIdx.z == 0) { W = Wk; bias = bk; out = kout; }
    else                 { W = Wq; bias = bq; out = qout; }

    __shared__ __align__(16) float As[32][68];
    __shared__ __align__(16) float Bs[32][68];

    const int tid = threadIdx.x;
    const int m0_blk = blockIdx.y * 64;
    const int n0_blk = blockIdx.x * 64;
    const int tx = tid & 15, ty = tid >> 4;
    const int mm = ty * 4, nn = tx * 4;

    float acc[4][4] = {};
    const int a_kq = tid & 7;
    const int a_m  = tid >> 3;
    const int b_n4 = (tid & 15) * 4;
    const int b_k  = tid >> 4;

    for (int k0 = 0; k0 < C_DIM; k0 += 32) {
#pragma unroll
        for (int half = 0; half < 2; ++half) {
            const int m = a_m + half * 32;
            const float4 av = *reinterpret_cast<const float4*>(
                &x[(size_t)(m0_blk + m) * C_DIM + k0 + a_kq * 4]);
            As[a_kq * 4 + 0][m] = av.x;
            As[a_kq * 4 + 1][m] = av.y;
            As[a_kq * 4 + 2][m] = av.z;
            As[a_kq * 4 + 3][m] = av.w;
        }
#pragma unroll
        for (int half = 0; half < 2; ++half) {
            const int kk = b_k + half * 16;
            *reinterpret_cast<float4*>(&Bs[kk][b_n4]) =
                *reinterpret_cast<const float4*>(
                    &W[(size_t)(k0 + kk) * C_DIM + n0_blk + b_n4]);
        }
        __syncthreads();
#pragma unroll
        for (int kk = 0; kk < 32; ++kk) {
            const float4 a4 = *reinterpret_cast<const float4*>(&As[kk][mm]);
            const float4 b4 = *reinterpret_cast<const float4*>(&Bs[kk][nn]);
            const float a_[4] = {a4.x, a4.y, a4.z, a4.w};
            const float b_[4] = {b4.x, b4.y, b4.z, b4.w};
#pragma unroll
            for (int i = 0; i < 4; ++i)
#pragma unroll
                for (int j = 0; j < 4; ++j)
                    acc[i][j] = fmaf(a_[i], b_[j], acc[i][j]);
        }
        __syncthreads();
    }

    const int h = blockIdx.x;
    const float4 bv = *reinterpret_cast<const float4*>(&bias[n0_blk + nn]);
    const float b_[4] = {bv.x, bv.y, bv.z, bv.w};
#pragma unroll
    for (int i = 0; i < 4; ++i) {
        const int t = m0_blk + mm + i;
        ushort4 o;
        o.x = bf16bits(acc[i][0] + b_[0]);
        o.y = bf16bits(acc[i][1] + b_[1]);
        o.z = bf16bits(acc[i][2] + b_[2]);
        o.w = bf16bits(acc[i][3] + b_[3]);
        *reinterpret_cast<ushort4*>(
            &out[((size_t)h * T_LEN + t) * D_DIM + nn]) = o;
    }
}

// ---------------------------------------------------------------------------
// MFMA flash attention (reference's swapped roles), head-major + XCD swizzle
// + double-buffered Q/V register prefetch. One wave per (head, 32-row i-tile).
// ---------------------------------------------------------------------------
__global__ __launch_bounds__(256) void attn_mfma(
    const __hip_bfloat16* __restrict__ K,   // [H][T][64]
    const __hip_bfloat16* __restrict__ Q,   // [H][T][64]
    const __hip_bfloat16* __restrict__ Vt,  // [H][64][T]
    float* __restrict__ y) {                // [T][768]

    const int bid = blockIdx.x;
    const int wg = (bid & 7) * 48 + (bid >> 3);   // XCD chunks: 1.5 heads/XCD
    const int u  = wg * 4 + (threadIdx.x >> 6);   // 0..1535
    const int h  = u >> 7;                        // head-major
    const int itile = 127 - (u & 127);            // heavy-first within head
    const int iw = itile * 32;
    const int lane = threadIdx.x & 63;
    const int lm = lane & 31;
    const int hi = lane >> 5;

    const __hip_bfloat16* kp = K + ((size_t)h * T_LEN + iw + lm) * D_DIM + hi * 8;
    const bf16x8 bk0 = *reinterpret_cast<const bf16x8*>(kp + 0);
    const bf16x8 bk1 = *reinterpret_cast<const bf16x8*>(kp + 16);
    const bf16x8 bk2 = *reinterpret_cast<const bf16x8*>(kp + 32);
    const bf16x8 bk3 = *reinterpret_cast<const bf16x8*>(kp + 48);

    f32x16 acc0 = {}, acc1 = {};
    float m = -1e30f, lsum = 0.0f;

    const __hip_bfloat16* qrow  = Q  + ((size_t)h * T_LEN + lm) * D_DIM + hi * 8;
    const __hip_bfloat16* vrow0 = Vt + ((size_t)h * D_DIM + lm) * T_LEN + hi * 8;
    const __hip_bfloat16* vrow1 = vrow0 + (size_t)32 * T_LEN;

    bf16x8 qA0, qA1, qA2, qA3, vA0, vA1, vA2, vA3;
    bf16x8 qB0, qB1, qB2, qB3, vB0, vB1, vB2, vB3;

#define PREFETCH(S, J) do {                                              \
    const __hip_bfloat16* qp_ = qrow + (size_t)(J) * D_DIM;              \
    q##S##0 = *reinterpret_cast<const bf16x8*>(qp_ + 0);                 \
    q##S##1 = *reinterpret_cast<const bf16x8*>(qp_ + 16);                \
    q##S##2 = *reinterpret_cast<const bf16x8*>(qp_ + 32);                \
    q##S##3 = *reinterpret_cast<const bf16x8*>(qp_ + 48);                \
    v##S##0 = *reinterpret_cast<const bf16x8*>(vrow0 + (J));             \
    v##S##1 = *reinterpret_cast<const bf16x8*>(vrow0 + (J) + 16);        \
    v##S##2 = *reinterpret_cast<const bf16x8*>(vrow1 + (J));             \
    v##S##3 = *reinterpret_cast<const bf16x8*>(vrow1 + (J) + 16);        \
} while (0)

#define COMPUTE(S, J) do {                                               \
    f32x16 s = {};                                                       \
    s = __builtin_amdgcn_mfma_f32_32x32x16_bf16(q##S##0, bk0, s, 0,0,0); \
    s = __builtin_amdgcn_mfma_f32_32x32x16_bf16(q##S##1, bk1, s, 0,0,0); \
    s = __builtin_amdgcn_mfma_f32_32x32x16_bf16(q##S##2, bk2, s, 0,0,0); \
    s = __builtin_amdgcn_mfma_f32_32x32x16_bf16(q##S##3, bk3, s, 0,0,0); \
    if ((J) == iw) {                                                     \
        _Pragma("unroll")                                                \
        for (int r = 0; r < 16; ++r) {                                   \
            const int jr = (r & 3) + 8 * (r >> 2) + 4 * hi;              \
            if (jr > lm) s[r] = -1e30f;                                  \
        }                                                                \
    }                                                                    \
    float pmax = s[0];                                                   \
    _Pragma("unroll")                                                    \
    for (int r = 1; r < 16; ++r) pmax = fmaxf(pmax, s[r]);               \
    pmax = fmaxf(pmax, __shfl_xor(pmax, 32));                            \
    if (__any(pmax > m + 8.0f)) {                                        \
        const float mn = fmaxf(m, pmax);                                 \
        const float sc = __expf(m - mn);                                 \
        lsum *= sc;                                                      \
        _Pragma("unroll")                                                \
        for (int r = 0; r < 16; ++r) {                                   \
            const float sr = __shfl(sc, (r & 3) + 8 * (r >> 2) + 4 * hi);\
            acc0[r] *= sr;                                               \
            acc1[r] *= sr;                                               \
        }                                                                \
        m = mn;                                                          \
    }                                                                    \
    float p[16];                                                         \
    _Pragma("unroll")                                                    \
    for (int r = 0; r < 16; ++r) p[r] = __expf(s[r] - m);                \
    float ls = 0.0f;                                                     \
    _Pragma("unroll")                                                    \
    for (int r = 0; r < 16; ++r) ls += p[r];                             \
    lsum += ls;                                                          \
    unsigned int w[8];                                                   \
    _Pragma("unroll")                                                    \
    for (int k = 0; k < 8; ++k)                                          \
        w[k] = (unsigned int)bf16bits(p[2 * k]) |                        \
               ((unsigned int)bf16bits(p[2 * k + 1]) << 16);             \
    unsigned int pw[8];                                                  \
    _Pragma("unroll")                                                    \
    for (int k = 0; k < 8; ++k) pw[k] = __shfl_xor((int)w[k], 32);       \
    const uint4 a0u = hi ? make_uint4(pw[2], pw[3], w[2], w[3])          \
                         : make_uint4(w[0], w[1], pw[0], pw[1]);         \
    const uint4 a1u = hi ? make_uint4(pw[6], pw[7], w[6], w[7])          \
                         : make_uint4(w[4], w[5], pw[4], pw[5]);         \
    const bf16x8 pa0 = __builtin_bit_cast(bf16x8, a0u);                  \
    const bf16x8 pa1 = __builtin_bit_cast(bf16x8, a1u);                  \
    acc0 = __builtin_amdgcn_mfma_f32_32x32x16_bf16(pa0, v##S##0, acc0, 0,0,0); \
    acc0 = __builtin_amdgcn_mfma_f32_32x32x16_bf16(pa1, v##S##1, acc0, 0,0,0); \
    acc1 = __builtin_amdgcn_mfma_f32_32x32x16_bf16(pa0, v##S##2, acc1, 0,0,0); \
    acc1 = __builtin_amdgcn_mfma_f32_32x32x16_bf16(pa1, v##S##3, acc1, 0,0,0); \
} while (0)

    PREFETCH(A, 0);
    int j0 = 0;
    for (;;) {
        if (j0 + 32 <= iw) PREFETCH(B, j0 + 32);
        COMPUTE(A, j0);
        j0 += 32;
        if (j0 > iw) break;
        if (j0 + 32 <= iw) PREFETCH(A, j0 + 32);
        COMPUTE(B, j0);
        j0 += 32;
        if (j0 > iw) break;
    }
#undef PREFETCH
#undef COMPUTE

    const float lt = lsum + __shfl_xor(lsum, 32);
    const float linv = 1.0f / lt;
#pragma unroll
    for (int r = 0; r < 16; ++r) {
        const int cr = (r & 3) + 8 * (r >> 2) + 4 * hi;
        const int row = iw + cr;
        const float li = __shfl(linv, cr);
        y[(size_t)row * C_DIM + h * D_DIM + lm]      = acc0[r] * li;
        y[(size_t)row * C_DIM + h * D_DIM + 32 + lm] = acc1[r] * li;
    }
}

// ---------------------------------------------------------------------------
extern "C" void kernel_launch(void* const* d_in, const int* in_sizes, int n_in,
                              void* d_out, int out_size, void* d_ws, size_t ws_size,
                              hipStream_t stream) {
    const float* x  = (const float*)d_in[0];
    const float* Wk = (const float*)d_in[1];
    const float* bk = (const float*)d_in[2];
    const float* Wq = (const float*)d_in[3];
    const float* bq = (const float*)d_in[4];
    float* out = (float*)d_out;

    const size_t np = (size_t)T_LEN * C_DIM;          // 3,145,728
    __hip_bfloat16* kbuf  = (__hip_bfloat16*)d_ws;    // [H][T][64]
    __hip_bfloat16* qbuf  = kbuf + np;                // [H][T][64]
    __hip_bfloat16* vtbuf = qbuf + np;                // [H][64][T]
    __hip_bfloat16* wtbuf = vtbuf + np;               // [2][768][768]

    // xhi/xlo overlay d_out: 2*np bf16 == out_size floats exactly; dead
    // before attn_mfma rewrites d_out with y.
    __hip_bfloat16* xhi = (__hip_bfloat16*)d_out;     // [T][C]
    __hip_bfloat16* xlo = xhi + np;                   // [T][C]

    const size_t need_fast =
        (3 * np + 2 * (size_t)C_DIM * C_DIM) * sizeof(__hip_bfloat16);  // ~21.2 MB

    dim3 gv(T_LEN / 64, C_DIM / 64);      // (64, 12)
    if (ws_size >= need_fast) {
        vtx_kernel<true><<<gv, 256, 0, stream>>>(x, vtbuf, xhi, xlo);
        dim3 gw(C_DIM / 64, C_DIM / 64, 2);
        wt_kernel<<<gw, 256, 0, stream>>>(Wk, Wq, wtbuf);
        proj_mfma<<<384, 256, 0, stream>>>(xhi, xlo, wtbuf, bk, bq, kbuf, qbuf);
    } else {
        // Round-3 validated fallback: 3*np bf16 ws only.
        vtx_kernel<false><<<gv, 256, 0, stream>>>(x, vtbuf, nullptr, nullptr);
        dim3 g1(C_DIM / 64, T_LEN / 64, 2);
        proj_gemm<<<g1, 256, 0, stream>>>(x, Wk, bk, Wq, bq, kbuf, qbuf);
    }

    attn_mfma<<<384, 256, 0, stream>>>(kbuf, qbuf, vtbuf, out);
}

// Round 8
// 311.118 us; speedup vs baseline: 1.2148x; 1.2148x over previous
//
#include <hip/hip_runtime.h>
#include <hip/hip_bf16.h>
#include <math.h>

#define T_LEN 4096
#define C_DIM 768
#define H_NUM 12
#define D_DIM 64

typedef __bf16 bf16x8 __attribute__((ext_vector_type(8)));
typedef float f32x16 __attribute__((ext_vector_type(16)));

static __device__ __forceinline__ unsigned short bf16bits(float f) {
    return __builtin_bit_cast(unsigned short, __float2bfloat16(f));
}

template <typename TP>
static __device__ __forceinline__ void stp(TP* p, float v) {
    if constexpr (sizeof(TP) == 4) *p = v;
    else *p = __float2bfloat16(v);
}
template <typename TP>
static __device__ __forceinline__ float ldp(const TP* p) {
    if constexpr (sizeof(TP) == 4) return *p;
    else return __bfloat162float(*p);
}

// ---------------------------------------------------------------------------
// Prep: Vt[h][d][t] = bf16(x[t][h*64+d]); if WX also xhi/xlo bf16 split of x.
// ---------------------------------------------------------------------------
template <bool WX>
__global__ __launch_bounds__(256) void vtx_kernel(
    const float* __restrict__ x,
    __hip_bfloat16* __restrict__ Vt,
    __hip_bfloat16* __restrict__ xhi,
    __hip_bfloat16* __restrict__ xlo) {
    __shared__ float tile[64][65];
    const int t0 = blockIdx.x * 64;
    const int c0 = blockIdx.y * 64;
    const int tid = threadIdx.x;
    const int cl = tid & 63;
    const int rq = tid >> 6;
#pragma unroll
    for (int rr = 0; rr < 16; ++rr) {
        const int row = rr * 4 + rq;
        const float v = x[(size_t)(t0 + row) * C_DIM + c0 + cl];
        tile[row][cl] = v;
        if (WX) {
            const __hip_bfloat16 hb = __float2bfloat16(v);
            xhi[(size_t)(t0 + row) * C_DIM + c0 + cl] = hb;
            xlo[(size_t)(t0 + row) * C_DIM + c0 + cl] =
                __float2bfloat16(v - __bfloat162float(hb));
        }
    }
    __syncthreads();
#pragma unroll
    for (int cc = 0; cc < 16; ++cc) {
        const int c = cc * 4 + rq;
        const int gc = c0 + c;
        const int h = gc >> 6, d = gc & 63;
        Vt[((size_t)h * D_DIM + d) * T_LEN + t0 + cl] =
            __float2bfloat16(tile[cl][c]);
    }
}

// ---------------------------------------------------------------------------
// Prep: Wt[w][n][k] = bf16(W_w[k][n]).
// ---------------------------------------------------------------------------
__global__ __launch_bounds__(256) void wt_kernel(
    const float* __restrict__ Wk, const float* __restrict__ Wq,
    __hip_bfloat16* __restrict__ wt) {
    const float* W = blockIdx.z ? Wq : Wk;
    __hip_bfloat16* o = wt + (size_t)blockIdx.z * C_DIM * C_DIM;
    __shared__ float tile[64][65];
    const int k0 = blockIdx.x * 64;
    const int n0 = blockIdx.y * 64;
    const int tid = threadIdx.x;
    const int cl = tid & 63;
    const int rq = tid >> 6;
#pragma unroll
    for (int rr = 0; rr < 16; ++rr) {
        const int row = rr * 4 + rq;
        tile[row][cl] = W[(size_t)(k0 + row) * C_DIM + n0 + cl];
    }
    __syncthreads();
#pragma unroll
    for (int rr = 0; rr < 16; ++rr) {
        const int row = rr * 4 + rq;
        o[(size_t)(n0 + row) * C_DIM + k0 + cl] =
            __float2bfloat16(tile[cl][row]);
    }
}

// ---------------------------------------------------------------------------
// Projection via bf16 MFMA, split-x compensation (validated round 6).
// ---------------------------------------------------------------------------
__global__ __launch_bounds__(256) void proj_mfma(
    const __hip_bfloat16* __restrict__ xhi,
    const __hip_bfloat16* __restrict__ xlo,
    const __hip_bfloat16* __restrict__ wt,
    const float* __restrict__ bk, const float* __restrict__ bq,
    __hip_bfloat16* __restrict__ kout, __hip_bfloat16* __restrict__ qout) {

    const int bid = blockIdx.x;                  // 384
    const int wg = (bid & 7) * 48 + (bid >> 3);
    const int u  = wg * 4 + (threadIdx.x >> 6);
    const int mt = u / 24;
    const int r24 = u - mt * 24;
    const int wsel = r24 / 12;
    const int nt = r24 - wsel * 12;
    const int m0 = mt * 64, n0 = nt * 64;
    const int lane = threadIdx.x & 63;
    const int lm = lane & 31, hi = lane >> 5;

    const __hip_bfloat16* wb = wt + (size_t)wsel * C_DIM * C_DIM;
    const __hip_bfloat16* a0p = xhi + (size_t)(m0 + lm) * C_DIM + hi * 8;
    const __hip_bfloat16* a1p = a0p + 32 * C_DIM;
    const __hip_bfloat16* l0p = xlo + (size_t)(m0 + lm) * C_DIM + hi * 8;
    const __hip_bfloat16* l1p = l0p + 32 * C_DIM;
    const __hip_bfloat16* b0p = wb + (size_t)(n0 + lm) * C_DIM + hi * 8;
    const __hip_bfloat16* b1p = b0p + 32 * C_DIM;

    f32x16 acc00 = {}, acc01 = {}, acc10 = {}, acc11 = {};

#pragma unroll 4
    for (int k0 = 0; k0 < C_DIM; k0 += 16) {
        const bf16x8 a0 = *reinterpret_cast<const bf16x8*>(a0p + k0);
        const bf16x8 a1 = *reinterpret_cast<const bf16x8*>(a1p + k0);
        const bf16x8 b0 = *reinterpret_cast<const bf16x8*>(b0p + k0);
        const bf16x8 b1 = *reinterpret_cast<const bf16x8*>(b1p + k0);
        acc00 = __builtin_amdgcn_mfma_f32_32x32x16_bf16(a0, b0, acc00, 0, 0, 0);
        acc01 = __builtin_amdgcn_mfma_f32_32x32x16_bf16(a0, b1, acc01, 0, 0, 0);
        acc10 = __builtin_amdgcn_mfma_f32_32x32x16_bf16(a1, b0, acc10, 0, 0, 0);
        acc11 = __builtin_amdgcn_mfma_f32_32x32x16_bf16(a1, b1, acc11, 0, 0, 0);
        const bf16x8 l0 = *reinterpret_cast<const bf16x8*>(l0p + k0);
        const bf16x8 l1 = *reinterpret_cast<const bf16x8*>(l1p + k0);
        acc00 = __builtin_amdgcn_mfma_f32_32x32x16_bf16(l0, b0, acc00, 0, 0, 0);
        acc01 = __builtin_amdgcn_mfma_f32_32x32x16_bf16(l0, b1, acc01, 0, 0, 0);
        acc10 = __builtin_amdgcn_mfma_f32_32x32x16_bf16(l1, b0, acc10, 0, 0, 0);
        acc11 = __builtin_amdgcn_mfma_f32_32x32x16_bf16(l1, b1, acc11, 0, 0, 0);
    }

    const float* bias = wsel ? bq : bk;
    __hip_bfloat16* out = wsel ? qout : kout;
    const int h = nt;
    const float bv0 = bias[n0 + lm];
    const float bv1 = bias[n0 + 32 + lm];
#pragma unroll
    for (int r = 0; r < 16; ++r) {
        const int cr = (r & 3) + 8 * (r >> 2) + 4 * hi;
        const int t0r = m0 + cr;
        const int t1r = m0 + 32 + cr;
        out[((size_t)h * T_LEN + t0r) * D_DIM + lm]      = __float2bfloat16(acc00[r] + bv0);
        out[((size_t)h * T_LEN + t0r) * D_DIM + 32 + lm] = __float2bfloat16(acc01[r] + bv1);
        out[((size_t)h * T_LEN + t1r) * D_DIM + lm]      = __float2bfloat16(acc10[r] + bv0);
        out[((size_t)h * T_LEN + t1r) * D_DIM + 32 + lm] = __float2bfloat16(acc11[r] + bv1);
    }
}

// ---------------------------------------------------------------------------
// Legacy fp32 projection (round-3 validated) — only if ws is tiny.
// ---------------------------------------------------------------------------
__global__ __launch_bounds__(256) void proj_gemm(
    const float* __restrict__ x,
    const float* __restrict__ Wk, const float* __restrict__ bk,
    const float* __restrict__ Wq, const float* __restrict__ bq,
    __hip_bfloat16* __restrict__ kout, __hip_bfloat16* __restrict__ qout) {

    const float* W; const float* bias; __hip_bfloat16* out;
    if (blockIdx.z == 0) { W = Wk; bias = bk; out = kout; }
    else                 { W = Wq; bias = bq; out = qout; }

    __shared__ __align__(16) float As[32][68];
    __shared__ __align__(16) float Bs[32][68];

    const int tid = threadIdx.x;
    const int m0_blk = blockIdx.y * 64;
    const int n0_blk = blockIdx.x * 64;
    const int tx = tid & 15, ty = tid >> 4;
    const int mm = ty * 4, nn = tx * 4;
    float acc[4][4] = {};
    const int a_kq = tid & 7;
    const int a_m  = tid >> 3;
    const int b_n4 = (tid & 15) * 4;
    const int b_k  = tid >> 4;

    for (int k0 = 0; k0 < C_DIM; k0 += 32) {
#pragma unroll
        for (int half = 0; half < 2; ++half) {
            const int m = a_m + half * 32;
            const float4 av = *reinterpret_cast<const float4*>(
                &x[(size_t)(m0_blk + m) * C_DIM + k0 + a_kq * 4]);
            As[a_kq * 4 + 0][m] = av.x;
            As[a_kq * 4 + 1][m] = av.y;
            As[a_kq * 4 + 2][m] = av.z;
            As[a_kq * 4 + 3][m] = av.w;
        }
#pragma unroll
        for (int half = 0; half < 2; ++half) {
            const int kk = b_k + half * 16;
            *reinterpret_cast<float4*>(&Bs[kk][b_n4]) =
                *reinterpret_cast<const float4*>(
                    &W[(size_t)(k0 + kk) * C_DIM + n0_blk + b_n4]);
        }
        __syncthreads();
#pragma unroll
        for (int kk = 0; kk < 32; ++kk) {
            const float4 a4 = *reinterpret_cast<const float4*>(&As[kk][mm]);
            const float4 b4 = *reinterpret_cast<const float4*>(&Bs[kk][nn]);
            const float a_[4] = {a4.x, a4.y, a4.z, a4.w};
            const float b_[4] = {b4.x, b4.y, b4.z, b4.w};
#pragma unroll
            for (int i = 0; i < 4; ++i)
#pragma unroll
                for (int j = 0; j < 4; ++j)
                    acc[i][j] = fmaf(a_[i], b_[j], acc[i][j]);
        }
        __syncthreads();
    }

    const int h = blockIdx.x;
    const float4 bv = *reinterpret_cast<const float4*>(&bias[n0_blk + nn]);
    const float b_[4] = {bv.x, bv.y, bv.z, bv.w};
#pragma unroll
    for (int i = 0; i < 4; ++i) {
        const int t = m0_blk + mm + i;
        ushort4 o;
        o.x = bf16bits(acc[i][0] + b_[0]);
        o.y = bf16bits(acc[i][1] + b_[1]);
        o.z = bf16bits(acc[i][2] + b_[2]);
        o.w = bf16bits(acc[i][3] + b_[3]);
        *reinterpret_cast<ushort4*>(
            &out[((size_t)h * T_LEN + t) * D_DIM + nn]) = o;
    }
}

// ---------------------------------------------------------------------------
// Split-j flash attention (flash-decoding). Wave = (h, itile t, seg).
// seg covers j-tiles [seg*32, seg*32+ntiles). Partials: unnormalized acc +
// per-row (m, l) -> pacc/pml, merged exactly by attn_merge.
// Slot id == wave id u. Per head 320 slots:
//   t<32: 1 seg; t<64: 2; t<96: 3; t<128: 4.  Total 3840 waves, 960 blocks.
// ---------------------------------------------------------------------------
template <typename TP>
__global__ __launch_bounds__(256) void attn_split(
    const __hip_bfloat16* __restrict__ K,   // [H][T][64]
    const __hip_bfloat16* __restrict__ Q,   // [H][T][64]
    const __hip_bfloat16* __restrict__ Vt,  // [H][64][T]
    TP* __restrict__ pacc,                  // [3840][32*64]
    float* __restrict__ pml) {              // [3840][64] (m[32], l[32])

    const int bid = blockIdx.x;                    // 960 = 8 x 120
    const int wg  = (bid & 7) * 120 + (bid >> 3);  // XCD chunk swizzle
    const int u   = wg * 4 + (threadIdx.x >> 6);   // 0..3839
    const int h   = u / 320;
    const int s   = u - h * 320;
    int t, seg;
    if (s < 32)       { t = s; seg = 0; }
    else if (s < 96)  { const int q = s - 32;  t = 32 + (q >> 1); seg = q & 1; }
    else if (s < 192) { const int q = s - 96;  const int q3 = q / 3; t = 64 + q3; seg = q - 3 * q3; }
    else              { const int q = s - 192; t = 96 + (q >> 2); seg = q & 3; }
    const int iw = t * 32;
    const int ntiles = min(32, t + 1 - seg * 32);
    const int jbase = seg * 1024;

    const int lane = threadIdx.x & 63;
    const int lm = lane & 31;
    const int hi = lane >> 5;

    // K fragments (B-operand): lane holds K[iw+lm][16*ki + 8*hi .. +7]
    const __hip_bfloat16* kp = K + ((size_t)h * T_LEN + iw + lm) * D_DIM + hi * 8;
    const bf16x8 bk0 = *reinterpret_cast<const bf16x8*>(kp + 0);
    const bf16x8 bk1 = *reinterpret_cast<const bf16x8*>(kp + 16);
    const bf16x8 bk2 = *reinterpret_cast<const bf16x8*>(kp + 32);
    const bf16x8 bk3 = *reinterpret_cast<const bf16x8*>(kp + 48);

    f32x16 acc0 = {}, acc1 = {};
    float m = -1e30f, lsum = 0.0f;

    const __hip_bfloat16* qrow  = Q  + ((size_t)h * T_LEN + jbase + lm) * D_DIM + hi * 8;
    const __hip_bfloat16* vrow0 = Vt + ((size_t)h * D_DIM + lm) * T_LEN + jbase + hi * 8;
    const __hip_bfloat16* vrow1 = vrow0 + (size_t)32 * T_LEN;

    for (int c = 0; c < ntiles; ++c) {
        const int j0 = jbase + c * 32;
        const __hip_bfloat16* qp = qrow + (size_t)(c * 32) * D_DIM;
        const bf16x8 aq0 = *reinterpret_cast<const bf16x8*>(qp + 0);
        const bf16x8 aq1 = *reinterpret_cast<const bf16x8*>(qp + 16);
        const bf16x8 aq2 = *reinterpret_cast<const bf16x8*>(qp + 32);
        const bf16x8 aq3 = *reinterpret_cast<const bf16x8*>(qp + 48);

        f32x16 sc = {};
        sc = __builtin_amdgcn_mfma_f32_32x32x16_bf16(aq0, bk0, sc, 0, 0, 0);
        sc = __builtin_amdgcn_mfma_f32_32x32x16_bf16(aq1, bk1, sc, 0, 0, 0);
        sc = __builtin_amdgcn_mfma_f32_32x32x16_bf16(aq2, bk2, sc, 0, 0, 0);
        sc = __builtin_amdgcn_mfma_f32_32x32x16_bf16(aq3, bk3, sc, 0, 0, 0);

        if (j0 == iw) {  // diagonal tile (last seg only)
#pragma unroll
            for (int r = 0; r < 16; ++r) {
                const int jr = (r & 3) + 8 * (r >> 2) + 4 * hi;
                if (jr > lm) sc[r] = -1e30f;
            }
        }

        float pmax = sc[0];
#pragma unroll
        for (int r = 1; r < 16; ++r) pmax = fmaxf(pmax, sc[r]);
        pmax = fmaxf(pmax, __shfl_xor(pmax, 32));

        if (__any(pmax > m + 8.0f)) {
            const float mn = fmaxf(m, pmax);
            const float scl = __expf(m - mn);
            lsum *= scl;
#pragma unroll
            for (int r = 0; r < 16; ++r) {
                const float sr = __shfl(scl, (r & 3) + 8 * (r >> 2) + 4 * hi);
                acc0[r] *= sr;
                acc1[r] *= sr;
            }
            m = mn;
        }

        float p[16];
#pragma unroll
        for (int r = 0; r < 16; ++r) p[r] = __expf(sc[r] - m);
        float ls = 0.0f;
#pragma unroll
        for (int r = 0; r < 16; ++r) ls += p[r];
        lsum += ls;

        unsigned int w[8];
#pragma unroll
        for (int k = 0; k < 8; ++k)
            w[k] = (unsigned int)bf16bits(p[2 * k]) |
                   ((unsigned int)bf16bits(p[2 * k + 1]) << 16);
        unsigned int pw[8];
#pragma unroll
        for (int k = 0; k < 8; ++k) pw[k] = __shfl_xor((int)w[k], 32);

        const uint4 a0u = hi ? make_uint4(pw[2], pw[3], w[2], w[3])
                             : make_uint4(w[0], w[1], pw[0], pw[1]);
        const uint4 a1u = hi ? make_uint4(pw[6], pw[7], w[6], w[7])
                             : make_uint4(w[4], w[5], pw[4], pw[5]);
        const bf16x8 pa0 = __builtin_bit_cast(bf16x8, a0u);
        const bf16x8 pa1 = __builtin_bit_cast(bf16x8, a1u);

        const bf16x8 v00 = *reinterpret_cast<const bf16x8*>(vrow0 + c * 32);
        const bf16x8 v01 = *reinterpret_cast<const bf16x8*>(vrow0 + c * 32 + 16);
        const bf16x8 v10 = *reinterpret_cast<const bf16x8*>(vrow1 + c * 32);
        const bf16x8 v11 = *reinterpret_cast<const bf16x8*>(vrow1 + c * 32 + 16);

        acc0 = __builtin_amdgcn_mfma_f32_32x32x16_bf16(pa0, v00, acc0, 0, 0, 0);
        acc0 = __builtin_amdgcn_mfma_f32_32x32x16_bf16(pa1, v01, acc0, 0, 0, 0);
        acc1 = __builtin_amdgcn_mfma_f32_32x32x16_bf16(pa0, v10, acc1, 0, 0, 0);
        acc1 = __builtin_amdgcn_mfma_f32_32x32x16_bf16(pa1, v11, acc1, 0, 0, 0);
    }

    // store partial (slot == u)
    const float lrow = lsum + __shfl_xor(lsum, 32);
    if (hi == 0) {
        pml[(size_t)u * 64 + lm]      = m;
        pml[(size_t)u * 64 + 32 + lm] = lrow;
    }
    TP* pa = pacc + (size_t)u * 2048;
#pragma unroll
    for (int r = 0; r < 16; ++r) {
        const int cr = (r & 3) + 8 * (r >> 2) + 4 * hi;
        stp(&pa[cr * 64 + lm],      acc0[r]);
        stp(&pa[cr * 64 + 32 + lm], acc1[r]);
    }
}

// ---------------------------------------------------------------------------
// Merge partials: block per (h, t). Exact softmax recombination.
// ---------------------------------------------------------------------------
template <typename TP>
__global__ __launch_bounds__(256) void attn_merge(
    const TP* __restrict__ pacc, const float* __restrict__ pml,
    float* __restrict__ y) {
    const int b = blockIdx.x;          // 1536
    const int h = b / 128;
    const int t = b - h * 128;
    const int ns = t / 32 + 1;
    const int base = h * 320 +
        (t < 32 ? t : (t < 64 ? 32 + (t - 32) * 2
                              : (t < 96 ? 96 + (t - 64) * 3
                                        : 192 + (t - 96) * 4)));
    const int tid = threadIdx.x;
    const int row = tid >> 3;          // 0..31
    const int dq  = (tid & 7) * 8;     // 0..56

    float m0 = pml[(size_t)base * 64 + row];
    float l0 = pml[(size_t)base * 64 + 32 + row];
    float m1 = -1e30f, l1 = 0.f, m2 = -1e30f, l2 = 0.f, m3 = -1e30f, l3 = 0.f;
    if (ns > 1) { m1 = pml[(size_t)(base + 1) * 64 + row]; l1 = pml[(size_t)(base + 1) * 64 + 32 + row]; }
    if (ns > 2) { m2 = pml[(size_t)(base + 2) * 64 + row]; l2 = pml[(size_t)(base + 2) * 64 + 32 + row]; }
    if (ns > 3) { m3 = pml[(size_t)(base + 3) * 64 + row]; l3 = pml[(size_t)(base + 3) * 64 + 32 + row]; }
    const float M = fmaxf(fmaxf(m0, m1), fmaxf(m2, m3));
    const float w0 = __expf(m0 - M), w1 = __expf(m1 - M);
    const float w2 = __expf(m2 - M), w3 = __expf(m3 - M);
    const float L = l0 * w0 + l1 * w1 + l2 * w2 + l3 * w3;
    const float inv = 1.0f / L;

    float o[8] = {};
    {
        const TP* pa = pacc + (size_t)base * 2048 + row * 64 + dq;
#pragma unroll
        for (int k = 0; k < 8; ++k) o[k] += ldp(&pa[k]) * w0;
    }
    if (ns > 1) {
        const TP* pa = pacc + (size_t)(base + 1) * 2048 + row * 64 + dq;
#pragma unroll
        for (int k = 0; k < 8; ++k) o[k] += ldp(&pa[k]) * w1;
    }
    if (ns > 2) {
        const TP* pa = pacc + (size_t)(base + 2) * 2048 + row * 64 + dq;
#pragma unroll
        for (int k = 0; k < 8; ++k) o[k] += ldp(&pa[k]) * w2;
    }
    if (ns > 3) {
        const TP* pa = pacc + (size_t)(base + 3) * 2048 + row * 64 + dq;
#pragma unroll
        for (int k = 0; k < 8; ++k) o[k] += ldp(&pa[k]) * w3;
    }
    float* yp = &y[(size_t)(t * 32 + row) * C_DIM + h * D_DIM + dq];
    float4 o0, o1;
    o0.x = o[0] * inv; o0.y = o[1] * inv; o0.z = o[2] * inv; o0.w = o[3] * inv;
    o1.x = o[4] * inv; o1.y = o[5] * inv; o1.z = o[6] * inv; o1.w = o[7] * inv;
    *reinterpret_cast<float4*>(yp + 0) = o0;
    *reinterpret_cast<float4*>(yp + 4) = o1;
}

// ---------------------------------------------------------------------------
// Flat attention fallback (round-3 validated, 185 us): wave per (h, itile).
// ---------------------------------------------------------------------------
__global__ __launch_bounds__(256) void attn_flat(
    const __hip_bfloat16* __restrict__ K,
    const __hip_bfloat16* __restrict__ Q,
    const __hip_bfloat16* __restrict__ Vt,
    float* __restrict__ y) {

    const int u  = blockIdx.x * 4 + (threadIdx.x >> 6);
    const int h  = u % H_NUM;
    const int itile = (T_LEN / 32 - 1) - u / H_NUM;
    const int iw = itile * 32;
    const int lane = threadIdx.x & 63;
    const int lm = lane & 31;
    const int hi = lane >> 5;

    const __hip_bfloat16* kp = K + ((size_t)h * T_LEN + iw + lm) * D_DIM + hi * 8;
    const bf16x8 bk0 = *reinterpret_cast<const bf16x8*>(kp + 0);
    const bf16x8 bk1 = *reinterpret_cast<const bf16x8*>(kp + 16);
    const bf16x8 bk2 = *reinterpret_cast<const bf16x8*>(kp + 32);
    const bf16x8 bk3 = *reinterpret_cast<const bf16x8*>(kp + 48);

    f32x16 acc0 = {}, acc1 = {};
    float m = -1e30f, lsum = 0.0f;

    const __hip_bfloat16* qrow  = Q  + ((size_t)h * T_LEN + lm) * D_DIM + hi * 8;
    const __hip_bfloat16* vrow0 = Vt + ((size_t)h * D_DIM + lm) * T_LEN + hi * 8;
    const __hip_bfloat16* vrow1 = vrow0 + (size_t)32 * T_LEN;

    for (int j0 = 0; j0 <= iw; j0 += 32) {
        const __hip_bfloat16* qp = qrow + (size_t)j0 * D_DIM;
        const bf16x8 aq0 = *reinterpret_cast<const bf16x8*>(qp + 0);
        const bf16x8 aq1 = *reinterpret_cast<const bf16x8*>(qp + 16);
        const bf16x8 aq2 = *reinterpret_cast<const bf16x8*>(qp + 32);
        const bf16x8 aq3 = *reinterpret_cast<const bf16x8*>(qp + 48);

        f32x16 sc = {};
        sc = __builtin_amdgcn_mfma_f32_32x32x16_bf16(aq0, bk0, sc, 0, 0, 0);
        sc = __builtin_amdgcn_mfma_f32_32x32x16_bf16(aq1, bk1, sc, 0, 0, 0);
        sc = __builtin_amdgcn_mfma_f32_32x32x16_bf16(aq2, bk2, sc, 0, 0, 0);
        sc = __builtin_amdgcn_mfma_f32_32x32x16_bf16(aq3, bk3, sc, 0, 0, 0);

        if (j0 == iw) {
#pragma unroll
            for (int r = 0; r < 16; ++r) {
                const int jr = (r & 3) + 8 * (r >> 2) + 4 * hi;
                if (jr > lm) sc[r] = -1e30f;
            }
        }

        float pmax = sc[0];
#pragma unroll
        for (int r = 1; r < 16; ++r) pmax = fmaxf(pmax, sc[r]);
        pmax = fmaxf(pmax, __shfl_xor(pmax, 32));

        if (__any(pmax > m + 8.0f)) {
            const float mn = fmaxf(m, pmax);
            const float scl = __expf(m - mn);
            lsum *= scl;
#pragma unroll
            for (int r = 0; r < 16; ++r) {
                const float sr = __shfl(scl, (r & 3) + 8 * (r >> 2) + 4 * hi);
                acc0[r] *= sr;
                acc1[r] *= sr;
            }
            m = mn;
        }

        float p[16];
#pragma unroll
        for (int r = 0; r < 16; ++r) p[r] = __expf(sc[r] - m);
        float ls = 0.0f;
#pragma unroll
        for (int r = 0; r < 16; ++r) ls += p[r];
        lsum += ls;

        unsigned int w[8];
#pragma unroll
        for (int k = 0; k < 8; ++k)
            w[k] = (unsigned int)bf16bits(p[2 * k]) |
                   ((unsigned int)bf16bits(p[2 * k + 1]) << 16);
        unsigned int pw[8];
#pragma unroll
        for (int k = 0; k < 8; ++k) pw[k] = __shfl_xor((int)w[k], 32);

        const uint4 a0u = hi ? make_uint4(pw[2], pw[3], w[2], w[3])
                             : make_uint4(w[0], w[1], pw[0], pw[1]);
        const uint4 a1u = hi ? make_uint4(pw[6], pw[7], w[6], w[7])
                             : make_uint4(w[4], w[5], pw[4], pw[5]);
        const bf16x8 pa0 = __builtin_bit_cast(bf16x8, a0u);
        const bf16x8 pa1 = __builtin_bit_cast(bf16x8, a1u);

        const bf16x8 v00 = *reinterpret_cast<const bf16x8*>(vrow0 + j0);
        const bf16x8 v01 = *reinterpret_cast<const bf16x8*>(vrow0 + j0 + 16);
        const bf16x8 v10 = *reinterpret_cast<const bf16x8*>(vrow1 + j0);
        const bf16x8 v11 = *reinterpret_cast<const bf16x8*>(vrow1 + j0 + 16);

        acc0 = __builtin_amdgcn_mfma_f32_32x32x16_bf16(pa0, v00, acc0, 0, 0, 0);
        acc0 = __builtin_amdgcn_mfma_f32_32x32x16_bf16(pa1, v01, acc0, 0, 0, 0);
        acc1 = __builtin_amdgcn_mfma_f32_32x32x16_bf16(pa0, v10, acc1, 0, 0, 0);
        acc1 = __builtin_amdgcn_mfma_f32_32x32x16_bf16(pa1, v11, acc1, 0, 0, 0);
    }

    const float lt = lsum + __shfl_xor(lsum, 32);
    const float linv = 1.0f / lt;
#pragma unroll
    for (int r = 0; r < 16; ++r) {
        const int cr = (r & 3) + 8 * (r >> 2) + 4 * hi;
        const int row = iw + cr;
        const float li = __shfl(linv, cr);
        y[(size_t)row * C_DIM + h * D_DIM + lm]      = acc0[r] * li;
        y[(size_t)row * C_DIM + h * D_DIM + 32 + lm] = acc1[r] * li;
    }
}

// ---------------------------------------------------------------------------
extern "C" void kernel_launch(void* const* d_in, const int* in_sizes, int n_in,
                              void* d_out, int out_size, void* d_ws, size_t ws_size,
                              hipStream_t stream) {
    const float* x  = (const float*)d_in[0];
    const float* Wk = (const float*)d_in[1];
    const float* bk = (const float*)d_in[2];
    const float* Wq = (const float*)d_in[3];
    const float* bq = (const float*)d_in[4];
    float* out = (float*)d_out;

    const size_t np = (size_t)T_LEN * C_DIM;           // 3,145,728
    const size_t NSLOT = 3840;
    __hip_bfloat16* kbuf  = (__hip_bfloat16*)d_ws;     // [H][T][64]
    __hip_bfloat16* qbuf  = kbuf + np;                 // [H][T][64]
    __hip_bfloat16* vtbuf = qbuf + np;                 // [H][64][T]
    char* after_kqv = (char*)(vtbuf + np);             // offset 18,874,368
    __hip_bfloat16* wtbuf = (__hip_bfloat16*)after_kqv;  // [2][768][768] (dead after proj)

    // partials overlay wtbuf (wt dead once proj_mfma completes)
    const size_t wt_bytes   = 2 * (size_t)C_DIM * C_DIM * sizeof(__hip_bfloat16);
    const size_t pacc_f32_b = NSLOT * 2048 * sizeof(float);
    const size_t pacc_b16_b = NSLOT * 2048 * sizeof(__hip_bfloat16);
    const size_t pml_b      = NSLOT * 64 * sizeof(float);
    const size_t base_b     = 3 * np * sizeof(__hip_bfloat16);
    const size_t needC = base_b + wt_bytes;                 // 21.2 MB (proj_mfma)
    const size_t needB = base_b + pacc_b16_b + pml_b;       // 35.6 MB
    const size_t needA = base_b + pacc_f32_b + pml_b;       // 51.3 MB

    // xhi/xlo overlay d_out (dead before y written)
    __hip_bfloat16* xhi = (__hip_bfloat16*)d_out;
    __hip_bfloat16* xlo = xhi + np;

    dim3 gv(T_LEN / 64, C_DIM / 64);
    if (ws_size >= needC) {
        vtx_kernel<true><<<gv, 256, 0, stream>>>(x, vtbuf, xhi, xlo);
        dim3 gw(C_DIM / 64, C_DIM / 64, 2);
        wt_kernel<<<gw, 256, 0, stream>>>(Wk, Wq, wtbuf);
        proj_mfma<<<384, 256, 0, stream>>>(xhi, xlo, wtbuf, bk, bq, kbuf, qbuf);
    } else {
        vtx_kernel<false><<<gv, 256, 0, stream>>>(x, vtbuf, nullptr, nullptr);
        dim3 g1(C_DIM / 64, T_LEN / 64, 2);
        proj_gemm<<<g1, 256, 0, stream>>>(x, Wk, bk, Wq, bq, kbuf, qbuf);
    }

    if (ws_size >= needA) {
        float* pacc = (float*)after_kqv;
        float* pml  = (float*)(after_kqv + pacc_f32_b);
        attn_split<float><<<960, 256, 0, stream>>>(kbuf, qbuf, vtbuf, pacc, pml);
        attn_merge<float><<<1536, 256, 0, stream>>>(pacc, pml, out);
    } else if (ws_size >= needB) {
        __hip_bfloat16* pacc = (__hip_bfloat16*)after_kqv;
        float* pml = (float*)(after_kqv + pacc_b16_b);
        attn_split<__hip_bfloat16><<<960, 256, 0, stream>>>(kbuf, qbuf, vtbuf, pacc, pml);
        attn_merge<__hip_bfloat16><<<1536, 256, 0, stream>>>(pacc, pml, out);
    } else {
        attn_flat<<<384, 256, 0, stream>>>(kbuf, qbuf, vtbuf, out);
    }
}

// Round 10
// 232.358 us; speedup vs baseline: 1.6266x; 1.3390x over previous
//
#include <hip/hip_runtime.h>
#include <hip/hip_bf16.h>
#include <math.h>

#define T_LEN 4096
#define C_DIM 768
#define H_NUM 12
#define D_DIM 64

typedef __bf16 bf16x8 __attribute__((ext_vector_type(8)));
typedef float f32x16 __attribute__((ext_vector_type(16)));

static __device__ __forceinline__ unsigned short bf16bits(float f) {
    return __builtin_bit_cast(unsigned short, __float2bfloat16(f));
}

template <typename TP>
static __device__ __forceinline__ void stp(TP* p, float v) {
    if constexpr (sizeof(TP) == 4) *p = v;
    else *p = __float2bfloat16(v);
}
template <typename TP>
static __device__ __forceinline__ float ldp(const TP* p) {
    if constexpr (sizeof(TP) == 4) return *p;
    else return __bfloat162float(*p);
}

// ---------------------------------------------------------------------------
// Prep: Vt[h][d][t] = bf16(x[t][h*64+d]); if WX also xhi/xlo bf16 split of x.
// ---------------------------------------------------------------------------
template <bool WX>
__global__ __launch_bounds__(256) void vtx_kernel(
    const float* __restrict__ x,
    __hip_bfloat16* __restrict__ Vt,
    __hip_bfloat16* __restrict__ xhi,
    __hip_bfloat16* __restrict__ xlo) {
    __shared__ float tile[64][65];
    const int t0 = blockIdx.x * 64;
    const int c0 = blockIdx.y * 64;
    const int tid = threadIdx.x;
    const int cl = tid & 63;
    const int rq = tid >> 6;
#pragma unroll
    for (int rr = 0; rr < 16; ++rr) {
        const int row = rr * 4 + rq;
        const float v = x[(size_t)(t0 + row) * C_DIM + c0 + cl];
        tile[row][cl] = v;
        if (WX) {
            const __hip_bfloat16 hb = __float2bfloat16(v);
            xhi[(size_t)(t0 + row) * C_DIM + c0 + cl] = hb;
            xlo[(size_t)(t0 + row) * C_DIM + c0 + cl] =
                __float2bfloat16(v - __bfloat162float(hb));
        }
    }
    __syncthreads();
#pragma unroll
    for (int cc = 0; cc < 16; ++cc) {
        const int c = cc * 4 + rq;
        const int gc = c0 + c;
        const int h = gc >> 6, d = gc & 63;
        Vt[((size_t)h * D_DIM + d) * T_LEN + t0 + cl] =
            __float2bfloat16(tile[cl][c]);
    }
}

// ---------------------------------------------------------------------------
// Prep: Wt[w][n][k] = bf16(W_w[k][n]).
// ---------------------------------------------------------------------------
__global__ __launch_bounds__(256) void wt_kernel(
    const float* __restrict__ Wk, const float* __restrict__ Wq,
    __hip_bfloat16* __restrict__ wt) {
    const float* W = blockIdx.z ? Wq : Wk;
    __hip_bfloat16* o = wt + (size_t)blockIdx.z * C_DIM * C_DIM;
    __shared__ float tile[64][65];
    const int k0 = blockIdx.x * 64;
    const int n0 = blockIdx.y * 64;
    const int tid = threadIdx.x;
    const int cl = tid & 63;
    const int rq = tid >> 6;
#pragma unroll
    for (int rr = 0; rr < 16; ++rr) {
        const int row = rr * 4 + rq;
        tile[row][cl] = W[(size_t)(k0 + row) * C_DIM + n0 + cl];
    }
    __syncthreads();
#pragma unroll
    for (int rr = 0; rr < 16; ++rr) {
        const int row = rr * 4 + rq;
        o[(size_t)(n0 + row) * C_DIM + k0 + cl] =
            __float2bfloat16(tile[cl][row]);
    }
}

// ---------------------------------------------------------------------------
// Projection via bf16 MFMA, split-x compensation (validated round 6).
// ---------------------------------------------------------------------------
__global__ __launch_bounds__(256) void proj_mfma(
    const __hip_bfloat16* __restrict__ xhi,
    const __hip_bfloat16* __restrict__ xlo,
    const __hip_bfloat16* __restrict__ wt,
    const float* __restrict__ bk, const float* __restrict__ bq,
    __hip_bfloat16* __restrict__ kout, __hip_bfloat16* __restrict__ qout) {

    const int bid = blockIdx.x;                  // 384
    const int wg = (bid & 7) * 48 + (bid >> 3);
    const int u  = wg * 4 + (threadIdx.x >> 6);
    const int mt = u / 24;
    const int r24 = u - mt * 24;
    const int wsel = r24 / 12;
    const int nt = r24 - wsel * 12;
    const int m0 = mt * 64, n0 = nt * 64;
    const int lane = threadIdx.x & 63;
    const int lm = lane & 31, hi = lane >> 5;

    const __hip_bfloat16* wb = wt + (size_t)wsel * C_DIM * C_DIM;
    const __hip_bfloat16* a0p = xhi + (size_t)(m0 + lm) * C_DIM + hi * 8;
    const __hip_bfloat16* a1p = a0p + 32 * C_DIM;
    const __hip_bfloat16* l0p = xlo + (size_t)(m0 + lm) * C_DIM + hi * 8;
    const __hip_bfloat16* l1p = l0p + 32 * C_DIM;
    const __hip_bfloat16* b0p = wb + (size_t)(n0 + lm) * C_DIM + hi * 8;
    const __hip_bfloat16* b1p = b0p + 32 * C_DIM;

    f32x16 acc00 = {}, acc01 = {}, acc10 = {}, acc11 = {};

#pragma unroll 4
    for (int k0 = 0; k0 < C_DIM; k0 += 16) {
        const bf16x8 a0 = *reinterpret_cast<const bf16x8*>(a0p + k0);
        const bf16x8 a1 = *reinterpret_cast<const bf16x8*>(a1p + k0);
        const bf16x8 b0 = *reinterpret_cast<const bf16x8*>(b0p + k0);
        const bf16x8 b1 = *reinterpret_cast<const bf16x8*>(b1p + k0);
        acc00 = __builtin_amdgcn_mfma_f32_32x32x16_bf16(a0, b0, acc00, 0, 0, 0);
        acc01 = __builtin_amdgcn_mfma_f32_32x32x16_bf16(a0, b1, acc01, 0, 0, 0);
        acc10 = __builtin_amdgcn_mfma_f32_32x32x16_bf16(a1, b0, acc10, 0, 0, 0);
        acc11 = __builtin_amdgcn_mfma_f32_32x32x16_bf16(a1, b1, acc11, 0, 0, 0);
        const bf16x8 l0 = *reinterpret_cast<const bf16x8*>(l0p + k0);
        const bf16x8 l1 = *reinterpret_cast<const bf16x8*>(l1p + k0);
        acc00 = __builtin_amdgcn_mfma_f32_32x32x16_bf16(l0, b0, acc00, 0, 0, 0);
        acc01 = __builtin_amdgcn_mfma_f32_32x32x16_bf16(l0, b1, acc01, 0, 0, 0);
        acc10 = __builtin_amdgcn_mfma_f32_32x32x16_bf16(l1, b0, acc10, 0, 0, 0);
        acc11 = __builtin_amdgcn_mfma_f32_32x32x16_bf16(l1, b1, acc11, 0, 0, 0);
    }

    const float* bias = wsel ? bq : bk;
    __hip_bfloat16* out = wsel ? qout : kout;
    const int h = nt;
    const float bv0 = bias[n0 + lm];
    const float bv1 = bias[n0 + 32 + lm];
#pragma unroll
    for (int r = 0; r < 16; ++r) {
        const int cr = (r & 3) + 8 * (r >> 2) + 4 * hi;
        const int t0r = m0 + cr;
        const int t1r = m0 + 32 + cr;
        out[((size_t)h * T_LEN + t0r) * D_DIM + lm]      = __float2bfloat16(acc00[r] + bv0);
        out[((size_t)h * T_LEN + t0r) * D_DIM + 32 + lm] = __float2bfloat16(acc01[r] + bv1);
        out[((size_t)h * T_LEN + t1r) * D_DIM + lm]      = __float2bfloat16(acc10[r] + bv0);
        out[((size_t)h * T_LEN + t1r) * D_DIM + 32 + lm] = __float2bfloat16(acc11[r] + bv1);
    }
}

// ---------------------------------------------------------------------------
// Legacy fp32 projection (round-3 validated) — only if ws is tiny.
// ---------------------------------------------------------------------------
__global__ __launch_bounds__(256) void proj_gemm(
    const float* __restrict__ x,
    const float* __restrict__ Wk, const float* __restrict__ bk,
    const float* __restrict__ Wq, const float* __restrict__ bq,
    __hip_bfloat16* __restrict__ kout, __hip_bfloat16* __restrict__ qout) {

    const float* W; const float* bias; __hip_bfloat16* out;
    if (blockIdx.z == 0) { W = Wk; bias = bk; out = kout; }
    else                 { W = Wq; bias = bq; out = qout; }

    __shared__ __align__(16) float As[32][68];
    __shared__ __align__(16) float Bs[32][68];

    const int tid = threadIdx.x;
    const int m0_blk = blockIdx.y * 64;
    const int n0_blk = blockIdx.x * 64;
    const int tx = tid & 15, ty = tid >> 4;
    const int mm = ty * 4, nn = tx * 4;
    float acc[4][4] = {};
    const int a_kq = tid & 7;
    const int a_m  = tid >> 3;
    const int b_n4 = (tid & 15) * 4;
    const int b_k  = tid >> 4;

    for (int k0 = 0; k0 < C_DIM; k0 += 32) {
#pragma unroll
        for (int half = 0; half < 2; ++half) {
            const int m = a_m + half * 32;
            const float4 av = *reinterpret_cast<const float4*>(
                &x[(size_t)(m0_blk + m) * C_DIM + k0 + a_kq * 4]);
            As[a_kq * 4 + 0][m] = av.x;
            As[a_kq * 4 + 1][m] = av.y;
            As[a_kq * 4 + 2][m] = av.z;
            As[a_kq * 4 + 3][m] = av.w;
        }
#pragma unroll
        for (int half = 0; half < 2; ++half) {
            const int kk = b_k + half * 16;
            *reinterpret_cast<float4*>(&Bs[kk][b_n4]) =
                *reinterpret_cast<const float4*>(
                    &W[(size_t)(k0 + kk) * C_DIM + n0_blk + b_n4]);
        }
        __syncthreads();
#pragma unroll
        for (int kk = 0; kk < 32; ++kk) {
            const float4 a4 = *reinterpret_cast<const float4*>(&As[kk][mm]);
            const float4 b4 = *reinterpret_cast<const float4*>(&Bs[kk][nn]);
            const float a_[4] = {a4.x, a4.y, a4.z, a4.w};
            const float b_[4] = {b4.x, b4.y, b4.z, b4.w};
#pragma unroll
            for (int i = 0; i < 4; ++i)
#pragma unroll
                for (int j = 0; j < 4; ++j)
                    acc[i][j] = fmaf(a_[i], b_[j], acc[i][j]);
        }
        __syncthreads();
    }

    const int h = blockIdx.x;
    const float4 bv = *reinterpret_cast<const float4*>(&bias[n0_blk + nn]);
    const float b_[4] = {bv.x, bv.y, bv.z, bv.w};
#pragma unroll
    for (int i = 0; i < 4; ++i) {
        const int t = m0_blk + mm + i;
        ushort4 o;
        o.x = bf16bits(acc[i][0] + b_[0]);
        o.y = bf16bits(acc[i][1] + b_[1]);
        o.z = bf16bits(acc[i][2] + b_[2]);
        o.w = bf16bits(acc[i][3] + b_[3]);
        *reinterpret_cast<ushort4*>(
            &out[((size_t)h * T_LEN + t) * D_DIM + nn]) = o;
    }
}

// ---------------------------------------------------------------------------
// LDS-staged split-j flash attention.
// Block = 4 waves; wave w owns i-tile t = ib*4+w (32 rows, K in regs).
// Per 64-j step: stage Q[64j][64d] and Vt[64d][64j] tiles (8KB each) into
// double-buffered XOR-swizzled LDS via coalesced reg-staged loads; all 4
// waves read fragments with ds_read_b128 (slot ^ (row&7) -> even bank use).
// Blocks: per head 80 ordinals r -> (ib,seg); nseg(ib)=ib/8+1; seg <=32 tiles.
// Partial slot = (h*80 + r)*4 + w  -- keyed by ORDINAL r (dispatch order is
// reversed for heavy-first, but slots are not).
// ---------------------------------------------------------------------------
template <typename TP>
__global__ __launch_bounds__(256) void attn_split2(
    const __hip_bfloat16* __restrict__ K,   // [H][T][64]
    const __hip_bfloat16* __restrict__ Q,   // [H][T][64]
    const __hip_bfloat16* __restrict__ Vt,  // [H][64][T]
    TP* __restrict__ pacc,                  // [3840][32*64]
    float* __restrict__ pml) {              // [3840][64]

    __shared__ __align__(16) char QsB[2][8192];
    __shared__ __align__(16) char VsB[2][8192];

    const int bid = blockIdx.x;                    // 960 = 8 x 120
    const int wg  = (bid & 7) * 120 + (bid >> 3);  // XCD chunk swizzle
    const int hh  = wg / 80;
    const int r   = 79 - (wg - hh * 80);           // heavy-first dispatch
    int ib, s;
    if (r < 8)       { ib = r; s = 0; }
    else if (r < 24) { const int q = r - 8;  ib = 8 + (q >> 1);  s = q & 1; }
    else if (r < 48) { const int q = r - 24; ib = 16 + q / 3;    s = q - 3 * (q / 3); }
    else             { const int q = r - 48; ib = 24 + (q >> 2); s = q & 3; }

    const int tid  = threadIdx.x;
    const int wv   = tid >> 6;
    const int lane = tid & 63;
    const int lm   = lane & 31;
    const int hi   = lane >> 5;
    const int t    = ib * 4 + wv;          // wave's i-tile within head
    const int iw   = t * 32;

    const int jt0  = s * 32;                          // first j-tile
    const int jend = min((s + 1) * 32, ib * 4 + 4);   // exclusive
    const int nsteps = (jend - jt0) >> 1;             // 64-j steps (even)

    // K fragments (B-operand)
    const __hip_bfloat16* kp = K + ((size_t)hh * T_LEN + iw + lm) * D_DIM + hi * 8;
    const bf16x8 bk0 = *reinterpret_cast<const bf16x8*>(kp + 0);
    const bf16x8 bk1 = *reinterpret_cast<const bf16x8*>(kp + 16);
    const bf16x8 bk2 = *reinterpret_cast<const bf16x8*>(kp + 32);
    const bf16x8 bk3 = *reinterpret_cast<const bf16x8*>(kp + 48);

    // staging sources
    const __hip_bfloat16* qsc = Q  + ((size_t)hh * T_LEN + jt0 * 32) * D_DIM;
    const __hip_bfloat16* vsc = Vt + (size_t)hh * D_DIM * T_LEN + jt0 * 32;

    // swizzled LDS byte offsets for this thread's 2 chunks (same for Q and V)
    const int k0c = tid, k1c = tid + 256;
    const int lo0 = (k0c >> 3) * 128 + (((k0c & 7) ^ ((k0c >> 3) & 7)) << 4);
    const int lo1 = (k1c >> 3) * 128 + (((k1c & 7) ^ ((k1c >> 3) & 7)) << 4);
    const size_t vro0 = (size_t)(tid >> 3) * T_LEN + (tid & 7) * 8;
    const size_t vro1 = (size_t)((tid >> 3) + 32) * T_LEN + (tid & 7) * 8;

    // prologue: stage step 0
    uint4 rq0 = *reinterpret_cast<const uint4*>(qsc + (size_t)k0c * 8);
    uint4 rq1 = *reinterpret_cast<const uint4*>(qsc + (size_t)k1c * 8);
    uint4 rv0 = *reinterpret_cast<const uint4*>(vsc + vro0);
    uint4 rv1 = *reinterpret_cast<const uint4*>(vsc + vro1);
    *reinterpret_cast<uint4*>(QsB[0] + lo0) = rq0;
    *reinterpret_cast<uint4*>(QsB[0] + lo1) = rq1;
    *reinterpret_cast<uint4*>(VsB[0] + lo0) = rv0;
    *reinterpret_cast<uint4*>(VsB[0] + lo1) = rv1;
    __syncthreads();

    f32x16 acc0 = {}, acc1 = {};
    float m = -1e30f, lsum = 0.0f;

#define COMPUTE(SUB) do {                                                     \
    const int jt_ = jt0 + st * 2 + (SUB);                                     \
    if (jt_ <= t) {                                                           \
        const char* qb = QsB[cur];                                            \
        const char* vb = VsB[cur];                                            \
        const int qrow = (SUB) * 32 + lm;                                     \
        const int qsw = qrow & 7;                                             \
        const bf16x8 aq0 = *reinterpret_cast<const bf16x8*>(                  \
            qb + qrow * 128 + (((0 + hi) ^ qsw) << 4));                       \
        const bf16x8 aq1 = *reinterpret_cast<const bf16x8*>(                  \
            qb + qrow * 128 + (((2 + hi) ^ qsw) << 4));                       \
        const bf16x8 aq2 = *reinterpret_cast<const bf16x8*>(                  \
            qb + qrow * 128 + (((4 + hi) ^ qsw) << 4));                       \
        const bf16x8 aq3 = *reinterpret_cast<const bf16x8*>(                  \
            qb + qrow * 128 + (((6 + hi) ^ qsw) << 4));                       \
        f32x16 sc = {};                                                       \
        sc = __builtin_amdgcn_mfma_f32_32x32x16_bf16(aq0, bk0, sc, 0, 0, 0);  \
        sc = __builtin_amdgcn_mfma_f32_32x32x16_bf16(aq1, bk1, sc, 0, 0, 0);  \
        sc = __builtin_amdgcn_mfma_f32_32x32x16_bf16(aq2, bk2, sc, 0, 0, 0);  \
        sc = __builtin_amdgcn_mfma_f32_32x32x16_bf16(aq3, bk3, sc, 0, 0, 0);  \
        if (jt_ == t) {                                                       \
            _Pragma("unroll")                                                 \
            for (int rr = 0; rr < 16; ++rr) {                                 \
                const int jr = (rr & 3) + 8 * (rr >> 2) + 4 * hi;             \
                if (jr > lm) sc[rr] = -1e30f;                                 \
            }                                                                 \
        }                                                                     \
        float pmax = sc[0];                                                   \
        _Pragma("unroll")                                                     \
        for (int rr = 1; rr < 16; ++rr) pmax = fmaxf(pmax, sc[rr]);           \
        pmax = fmaxf(pmax, __shfl_xor(pmax, 32));                             \
        if (__any(pmax > m + 8.0f)) {                                         \
            const float mn = fmaxf(m, pmax);                                  \
            const float scl = __expf(m - mn);                                 \
            lsum *= scl;                                                      \
            _Pragma("unroll")                                                 \
            for (int rr = 0; rr < 16; ++rr) {                                 \
                const float sr = __shfl(scl, (rr & 3) + 8 * (rr >> 2) + 4 * hi); \
                acc0[rr] *= sr;                                               \
                acc1[rr] *= sr;                                               \
            }                                                                 \
            m = mn;                                                           \
        }                                                                     \
        float p[16];                                                          \
        _Pragma("unroll")                                                     \
        for (int rr = 0; rr < 16; ++rr) p[rr] = __expf(sc[rr] - m);           \
        float ls = 0.0f;                                                      \
        _Pragma("unroll")                                                     \
        for (int rr = 0; rr < 16; ++rr) ls += p[rr];                          \
        lsum += ls;                                                           \
        unsigned int w_[8];                                                   \
        _Pragma("unroll")                                                     \
        for (int kk = 0; kk < 8; ++kk)                                        \
            w_[kk] = (unsigned int)bf16bits(p[2 * kk]) |                      \
                     ((unsigned int)bf16bits(p[2 * kk + 1]) << 16);           \
        unsigned int pw_[8];                                                  \
        _Pragma("unroll")                                                     \
        for (int kk = 0; kk < 8; ++kk) pw_[kk] = __shfl_xor((int)w_[kk], 32); \
        const uint4 a0u = hi ? make_uint4(pw_[2], pw_[3], w_[2], w_[3])       \
                             : make_uint4(w_[0], w_[1], pw_[0], pw_[1]);      \
        const uint4 a1u = hi ? make_uint4(pw_[6], pw_[7], w_[6], w_[7])       \
                             : make_uint4(w_[4], w_[5], pw_[4], pw_[5]);      \
        const bf16x8 pa0 = __builtin_bit_cast(bf16x8, a0u);                   \
        const bf16x8 pa1 = __builtin_bit_cast(bf16x8, a1u);                   \
        const int d0 = lm, d1 = 32 + lm;                                      \
        const int vsw = lm & 7;                                               \
        const bf16x8 v00 = *reinterpret_cast<const bf16x8*>(                  \
            vb + d0 * 128 + ((((SUB) * 4 + 0 + hi) ^ vsw) << 4));             \
        const bf16x8 v01 = *reinterpret_cast<const bf16x8*>(                  \
            vb + d0 * 128 + ((((SUB) * 4 + 2 + hi) ^ vsw) << 4));             \
        const bf16x8 v10 = *reinterpret_cast<const bf16x8*>(                  \
            vb + d1 * 128 + ((((SUB) * 4 + 0 + hi) ^ vsw) << 4));             \
        const bf16x8 v11 = *reinterpret_cast<const bf16x8*>(                  \
            vb + d1 * 128 + ((((SUB) * 4 + 2 + hi) ^ vsw) << 4));             \
        acc0 = __builtin_amdgcn_mfma_f32_32x32x16_bf16(pa0, v00, acc0, 0,0,0);\
        acc0 = __builtin_amdgcn_mfma_f32_32x32x16_bf16(pa1, v01, acc0, 0,0,0);\
        acc1 = __builtin_amdgcn_mfma_f32_32x32x16_bf16(pa0, v10, acc1, 0,0,0);\
        acc1 = __builtin_amdgcn_mfma_f32_32x32x16_bf16(pa1, v11, acc1, 0,0,0);\
    }                                                                         \
} while (0)

    int cur = 0;
    for (int st = 0; st < nsteps; ++st) {
        const bool more = (st + 1 < nsteps);
        if (more) {  // issue next-step loads early (hidden under compute)
            rq0 = *reinterpret_cast<const uint4*>(qsc + (size_t)(st + 1) * 4096 + (size_t)k0c * 8);
            rq1 = *reinterpret_cast<const uint4*>(qsc + (size_t)(st + 1) * 4096 + (size_t)k1c * 8);
            rv0 = *reinterpret_cast<const uint4*>(vsc + vro0 + (size_t)(st + 1) * 64);
            rv1 = *reinterpret_cast<const uint4*>(vsc + vro1 + (size_t)(st + 1) * 64);
        }
        COMPUTE(0);
        COMPUTE(1);
        if (more) {
            char* qn = QsB[cur ^ 1];
            char* vn = VsB[cur ^ 1];
            *reinterpret_cast<uint4*>(qn + lo0) = rq0;
            *reinterpret_cast<uint4*>(qn + lo1) = rq1;
            *reinterpret_cast<uint4*>(vn + lo0) = rv0;
            *reinterpret_cast<uint4*>(vn + lo1) = rv1;
        }
        __syncthreads();
        cur ^= 1;
    }
#undef COMPUTE

    // store partial: slot keyed by ordinal r
    const int slot = (hh * 80 + r) * 4 + wv;
    const float lrow = lsum + __shfl_xor(lsum, 32);
    if (hi == 0) {
        pml[(size_t)slot * 64 + lm]      = m;
        pml[(size_t)slot * 64 + 32 + lm] = lrow;
    }
    TP* pa = pacc + (size_t)slot * 2048;
#pragma unroll
    for (int rr = 0; rr < 16; ++rr) {
        const int cr = (rr & 3) + 8 * (rr >> 2) + 4 * hi;
        stp(&pa[cr * 64 + lm],      acc0[rr]);
        stp(&pa[cr * 64 + 32 + lm], acc1[rr]);
    }
}

// ---------------------------------------------------------------------------
// Merge partials: block per (h, t). Seg s of i-block ib lives at ordinal
// bb(ib)+s  ->  slot = (h*80 + bb + s)*4 + w.   (FIX: no 79- reversal here;
// attn_split2 keys slots by ordinal, not by dispatch position.)
// ---------------------------------------------------------------------------
template <typename TP>
__global__ __launch_bounds__(256) void attn_merge(
    const TP* __restrict__ pacc, const float* __restrict__ pml,
    float* __restrict__ y) {
    const int b = blockIdx.x;          // 1536
    const int h = b / 128;
    const int t = b - h * 128;
    const int ib = t >> 2, w = t & 3;
    const int ns = (t >> 5) + 1;
    int bb;
    if (ib < 8)       bb = ib;
    else if (ib < 16) bb = 8 + (ib - 8) * 2;
    else if (ib < 24) bb = 24 + (ib - 16) * 3;
    else              bb = 48 + (ib - 24) * 4;
    const int slot0 = (h * 80 + bb) * 4 + w;        // seg s -> slot0 + s*4
    const int tid = threadIdx.x;
    const int row = tid >> 3;          // 0..31
    const int dq  = (tid & 7) * 8;     // 0..56

    float m0 = pml[(size_t)slot0 * 64 + row];
    float l0 = pml[(size_t)slot0 * 64 + 32 + row];
    float m1 = -1e30f, l1 = 0.f, m2 = -1e30f, l2 = 0.f, m3 = -1e30f, l3 = 0.f;
    if (ns > 1) { m1 = pml[(size_t)(slot0 + 4) * 64 + row];  l1 = pml[(size_t)(slot0 + 4) * 64 + 32 + row]; }
    if (ns > 2) { m2 = pml[(size_t)(slot0 + 8) * 64 + row];  l2 = pml[(size_t)(slot0 + 8) * 64 + 32 + row]; }
    if (ns > 3) { m3 = pml[(size_t)(slot0 + 12) * 64 + row]; l3 = pml[(size_t)(slot0 + 12) * 64 + 32 + row]; }
    const float M = fmaxf(fmaxf(m0, m1), fmaxf(m2, m3));
    const float w0 = __expf(m0 - M), w1 = __expf(m1 - M);
    const float w2 = __expf(m2 - M), w3 = __expf(m3 - M);
    const float L = l0 * w0 + l1 * w1 + l2 * w2 + l3 * w3;
    const float inv = 1.0f / L;

    float o[8] = {};
    {
        const TP* pa = pacc + (size_t)slot0 * 2048 + row * 64 + dq;
#pragma unroll
        for (int k = 0; k < 8; ++k) o[k] += ldp(&pa[k]) * w0;
    }
    if (ns > 1) {
        const TP* pa = pacc + (size_t)(slot0 + 4) * 2048 + row * 64 + dq;
#pragma unroll
        for (int k = 0; k < 8; ++k) o[k] += ldp(&pa[k]) * w1;
    }
    if (ns > 2) {
        const TP* pa = pacc + (size_t)(slot0 + 8) * 2048 + row * 64 + dq;
#pragma unroll
        for (int k = 0; k < 8; ++k) o[k] += ldp(&pa[k]) * w2;
    }
    if (ns > 3) {
        const TP* pa = pacc + (size_t)(slot0 + 12) * 2048 + row * 64 + dq;
#pragma unroll
        for (int k = 0; k < 8; ++k) o[k] += ldp(&pa[k]) * w3;
    }
    float* yp = &y[(size_t)(t * 32 + row) * C_DIM + h * D_DIM + dq];
    float4 o0, o1;
    o0.x = o[0] * inv; o0.y = o[1] * inv; o0.z = o[2] * inv; o0.w = o[3] * inv;
    o1.x = o[4] * inv; o1.y = o[5] * inv; o1.z = o[6] * inv; o1.w = o[7] * inv;
    *reinterpret_cast<float4*>(yp + 0) = o0;
    *reinterpret_cast<float4*>(yp + 4) = o1;
}

// ---------------------------------------------------------------------------
// Flat attention fallback (round-3 validated): wave per (h, itile).
// ---------------------------------------------------------------------------
__global__ __launch_bounds__(256) void attn_flat(
    const __hip_bfloat16* __restrict__ K,
    const __hip_bfloat16* __restrict__ Q,
    const __hip_bfloat16* __restrict__ Vt,
    float* __restrict__ y) {

    const int u  = blockIdx.x * 4 + (threadIdx.x >> 6);
    const int h  = u % H_NUM;
    const int itile = (T_LEN / 32 - 1) - u / H_NUM;
    const int iw = itile * 32;
    const int lane = threadIdx.x & 63;
    const int lm = lane & 31;
    const int hi = lane >> 5;

    const __hip_bfloat16* kp = K + ((size_t)h * T_LEN + iw + lm) * D_DIM + hi * 8;
    const bf16x8 bk0 = *reinterpret_cast<const bf16x8*>(kp + 0);
    const bf16x8 bk1 = *reinterpret_cast<const bf16x8*>(kp + 16);
    const bf16x8 bk2 = *reinterpret_cast<const bf16x8*>(kp + 32);
    const bf16x8 bk3 = *reinterpret_cast<const bf16x8*>(kp + 48);

    f32x16 acc0 = {}, acc1 = {};
    float m = -1e30f, lsum = 0.0f;

    const __hip_bfloat16* qrow  = Q  + ((size_t)h * T_LEN + lm) * D_DIM + hi * 8;
    const __hip_bfloat16* vrow0 = Vt + ((size_t)h * D_DIM + lm) * T_LEN + hi * 8;
    const __hip_bfloat16* vrow1 = vrow0 + (size_t)32 * T_LEN;

    for (int j0 = 0; j0 <= iw; j0 += 32) {
        const __hip_bfloat16* qp = qrow + (size_t)j0 * D_DIM;
        const bf16x8 aq0 = *reinterpret_cast<const bf16x8*>(qp + 0);
        const bf16x8 aq1 = *reinterpret_cast<const bf16x8*>(qp + 16);
        const bf16x8 aq2 = *reinterpret_cast<const bf16x8*>(qp + 32);
        const bf16x8 aq3 = *reinterpret_cast<const bf16x8*>(qp + 48);

        f32x16 sc = {};
        sc = __builtin_amdgcn_mfma_f32_32x32x16_bf16(aq0, bk0, sc, 0, 0, 0);
        sc = __builtin_amdgcn_mfma_f32_32x32x16_bf16(aq1, bk1, sc, 0, 0, 0);
        sc = __builtin_amdgcn_mfma_f32_32x32x16_bf16(aq2, bk2, sc, 0, 0, 0);
        sc = __builtin_amdgcn_mfma_f32_32x32x16_bf16(aq3, bk3, sc, 0, 0, 0);

        if (j0 == iw) {
#pragma unroll
            for (int r = 0; r < 16; ++r) {
                const int jr = (r & 3) + 8 * (r >> 2) + 4 * hi;
                if (jr > lm) sc[r] = -1e30f;
            }
        }

        float pmax = sc[0];
#pragma unroll
        for (int r = 1; r < 16; ++r) pmax = fmaxf(pmax, sc[r]);
        pmax = fmaxf(pmax, __shfl_xor(pmax, 32));

        if (__any(pmax > m + 8.0f)) {
            const float mn = fmaxf(m, pmax);
            const float scl = __expf(m - mn);
            lsum *= scl;
#pragma unroll
            for (int r = 0; r < 16; ++r) {
                const float sr = __shfl(scl, (r & 3) + 8 * (r >> 2) + 4 * hi);
                acc0[r] *= sr;
                acc1[r] *= sr;
            }
            m = mn;
        }

        float p[16];
#pragma unroll
        for (int r = 0; r < 16; ++r) p[r] = __expf(sc[r] - m);
        float ls = 0.0f;
#pragma unroll
        for (int r = 0; r < 16; ++r) ls += p[r];
        lsum += ls;

        unsigned int w[8];
#pragma unroll
        for (int k = 0; k < 8; ++k)
            w[k] = (unsigned int)bf16bits(p[2 * k]) |
                   ((unsigned int)bf16bits(p[2 * k + 1]) << 16);
        unsigned int pw[8];
#pragma unroll
        for (int k = 0; k < 8; ++k) pw[k] = __shfl_xor((int)w[k], 32);

        const uint4 a0u = hi ? make_uint4(pw[2], pw[3], w[2], w[3])
                             : make_uint4(w[0], w[1], pw[0], pw[1]);
        const uint4 a1u = hi ? make_uint4(pw[6], pw[7], w[6], w[7])
                             : make_uint4(w[4], w[5], pw[4], pw[5]);
        const bf16x8 pa0 = __builtin_bit_cast(bf16x8, a0u);
        const bf16x8 pa1 = __builtin_bit_cast(bf16x8, a1u);

        const bf16x8 v00 = *reinterpret_cast<const bf16x8*>(vrow0 + j0);
        const bf16x8 v01 = *reinterpret_cast<const bf16x8*>(vrow0 + j0 + 16);
        const bf16x8 v10 = *reinterpret_cast<const bf16x8*>(vrow1 + j0);
        const bf16x8 v11 = *reinterpret_cast<const bf16x8*>(vrow1 + j0 + 16);

        acc0 = __builtin_amdgcn_mfma_f32_32x32x16_bf16(pa0, v00, acc0, 0, 0, 0);
        acc0 = __builtin_amdgcn_mfma_f32_32x32x16_bf16(pa1, v01, acc0, 0, 0, 0);
        acc1 = __builtin_amdgcn_mfma_f32_32x32x16_bf16(pa0, v10, acc1, 0, 0, 0);
        acc1 = __builtin_amdgcn_mfma_f32_32x32x16_bf16(pa1, v11, acc1, 0, 0, 0);
    }

    const float lt = lsum + __shfl_xor(lsum, 32);
    const float linv = 1.0f / lt;
#pragma unroll
    for (int r = 0; r < 16; ++r) {
        const int cr = (r & 3) + 8 * (r >> 2) + 4 * hi;
        const int row = iw + cr;
        const float li = __shfl(linv, cr);
        y[(size_t)row * C_DIM + h * D_DIM + lm]      = acc0[r] * li;
        y[(size_t)row * C_DIM + h * D_DIM + 32 + lm] = acc1[r] * li;
    }
}

// ---------------------------------------------------------------------------
extern "C" void kernel_launch(void* const* d_in, const int* in_sizes, int n_in,
                              void* d_out, int out_size, void* d_ws, size_t ws_size,
                              hipStream_t stream) {
    const float* x  = (const float*)d_in[0];
    const float* Wk = (const float*)d_in[1];
    const float* bk = (const float*)d_in[2];
    const float* Wq = (const float*)d_in[3];
    const float* bq = (const float*)d_in[4];
    float* out = (float*)d_out;

    const size_t np = (size_t)T_LEN * C_DIM;           // 3,145,728
    const size_t NSLOT = 3840;
    __hip_bfloat16* kbuf  = (__hip_bfloat16*)d_ws;     // [H][T][64]
    __hip_bfloat16* qbuf  = kbuf + np;                 // [H][T][64]
    __hip_bfloat16* vtbuf = qbuf + np;                 // [H][64][T]
    char* after_kqv = (char*)(vtbuf + np);
    __hip_bfloat16* wtbuf = (__hip_bfloat16*)after_kqv;  // dead after proj

    const size_t wt_bytes   = 2 * (size_t)C_DIM * C_DIM * sizeof(__hip_bfloat16);
    const size_t pacc_f32_b = NSLOT * 2048 * sizeof(float);
    const size_t pacc_b16_b = NSLOT * 2048 * sizeof(__hip_bfloat16);
    const size_t pml_b      = NSLOT * 64 * sizeof(float);
    const size_t base_b     = 3 * np * sizeof(__hip_bfloat16);
    const size_t needC = base_b + wt_bytes;                 // ~21.2 MB
    const size_t needB = base_b + pacc_b16_b + pml_b;       // ~35.6 MB
    const size_t needA = base_b + pacc_f32_b + pml_b;       // ~51.3 MB

    __hip_bfloat16* xhi = (__hip_bfloat16*)d_out;      // overlay d_out
    __hip_bfloat16* xlo = xhi + np;

    dim3 gv(T_LEN / 64, C_DIM / 64);
    if (ws_size >= needC) {
        vtx_kernel<true><<<gv, 256, 0, stream>>>(x, vtbuf, xhi, xlo);
        dim3 gw(C_DIM / 64, C_DIM / 64, 2);
        wt_kernel<<<gw, 256, 0, stream>>>(Wk, Wq, wtbuf);
        proj_mfma<<<384, 256, 0, stream>>>(xhi, xlo, wtbuf, bk, bq, kbuf, qbuf);
    } else {
        vtx_kernel<false><<<gv, 256, 0, stream>>>(x, vtbuf, nullptr, nullptr);
        dim3 g1(C_DIM / 64, T_LEN / 64, 2);
        proj_gemm<<<g1, 256, 0, stream>>>(x, Wk, bk, Wq, bq, kbuf, qbuf);
    }

    if (ws_size >= needA) {
        float* pacc = (float*)after_kqv;
        float* pml  = (float*)(after_kqv + pacc_f32_b);
        attn_split2<float><<<960, 256, 0, stream>>>(kbuf, qbuf, vtbuf, pacc, pml);
        attn_merge<float><<<1536, 256, 0, stream>>>(pacc, pml, out);
    } else if (ws_size >= needB) {
        __hip_bfloat16* pacc = (__hip_bfloat16*)after_kqv;
        float* pml = (float*)(after_kqv + pacc_b16_b);
        attn_split2<__hip_bfloat16><<<960, 256, 0, stream>>>(kbuf, qbuf, vtbuf, pacc, pml);
        attn_merge<__hip_bfloat16><<<1536, 256, 0, stream>>>(pacc, pml, out);
    } else {
        attn_flat<<<384, 256, 0, stream>>>(kbuf, qbuf, vtbuf, out);
    }
}

// Round 11
// 184.012 us; speedup vs baseline: 2.0539x; 1.2627x over previous
//
#include <hip/hip_runtime.h>
#include <hip/hip_bf16.h>
#include <math.h>

#define T_LEN 4096
#define C_DIM 768
#define H_NUM 12
#define D_DIM 64

typedef __bf16 bf16x8 __attribute__((ext_vector_type(8)));
typedef float f32x16 __attribute__((ext_vector_type(16)));

static __device__ __forceinline__ unsigned short bf16bits(float f) {
    return __builtin_bit_cast(unsigned short, __float2bfloat16(f));
}

template <typename TP>
static __device__ __forceinline__ void stp(TP* p, float v) {
    if constexpr (sizeof(TP) == 4) *p = v;
    else *p = __float2bfloat16(v);
}
template <typename TP>
static __device__ __forceinline__ float ldp(const TP* p) {
    if constexpr (sizeof(TP) == 4) return *p;
    else return __bfloat162float(*p);
}

// ---------------------------------------------------------------------------
// Fused prep: blocks 0..767 = vtx (Vt + xhi/xlo split), 768..1055 = Wt.
// ---------------------------------------------------------------------------
__global__ __launch_bounds__(256) void prep_kernel(
    const float* __restrict__ x,
    const float* __restrict__ Wk, const float* __restrict__ Wq,
    __hip_bfloat16* __restrict__ Vt,
    __hip_bfloat16* __restrict__ xhi,
    __hip_bfloat16* __restrict__ xlo,
    __hip_bfloat16* __restrict__ wt) {
    __shared__ float tile[64][65];
    const int bx = blockIdx.x;
    const int tid = threadIdx.x;
    const int cl = tid & 63;
    const int rq = tid >> 6;
    if (bx < 768) {
        const int t0 = (bx & 63) * 64;
        const int c0 = (bx >> 6) * 64;
#pragma unroll
        for (int rr = 0; rr < 16; ++rr) {
            const int row = rr * 4 + rq;
            const float v = x[(size_t)(t0 + row) * C_DIM + c0 + cl];
            tile[row][cl] = v;
            const __hip_bfloat16 hb = __float2bfloat16(v);
            xhi[(size_t)(t0 + row) * C_DIM + c0 + cl] = hb;
            xlo[(size_t)(t0 + row) * C_DIM + c0 + cl] =
                __float2bfloat16(v - __bfloat162float(hb));
        }
        __syncthreads();
#pragma unroll
        for (int cc = 0; cc < 16; ++cc) {
            const int c = cc * 4 + rq;
            const int gc = c0 + c;
            const int h = gc >> 6, d = gc & 63;
            Vt[((size_t)h * D_DIM + d) * T_LEN + t0 + cl] =
                __float2bfloat16(tile[cl][c]);
        }
    } else {
        const int bz = bx - 768;               // 0..287
        const int w  = bz / 144;
        const int rem = bz - w * 144;
        const int k0 = (rem % 12) * 64;
        const int n0 = (rem / 12) * 64;
        const float* W = w ? Wq : Wk;
        __hip_bfloat16* o = wt + (size_t)w * C_DIM * C_DIM;
#pragma unroll
        for (int rr = 0; rr < 16; ++rr) {
            const int row = rr * 4 + rq;
            tile[row][cl] = W[(size_t)(k0 + row) * C_DIM + n0 + cl];
        }
        __syncthreads();
#pragma unroll
        for (int rr = 0; rr < 16; ++rr) {
            const int row = rr * 4 + rq;       // n within tile
            o[(size_t)(n0 + row) * C_DIM + k0 + cl] =
                __float2bfloat16(tile[cl][row]);
        }
    }
}

// ---------------------------------------------------------------------------
// LDS-staged projection GEMM (split-x): out = (xhi+xlo)@W + b, bf16 [H][T][64].
// Block = 128m x 64n, 4 waves (wave wv: rows wv*32..wv*32+31, all 64 n).
// K-step 64: stage Ahi/Alo[128][64] + B[64][64] into XOR-swizzled LDS
// (same involution as attn_split2), 2-barrier loop.  768 blocks, XCD swizzle.
// ---------------------------------------------------------------------------
__global__ __launch_bounds__(256) void proj_mfma2(
    const __hip_bfloat16* __restrict__ xhi,
    const __hip_bfloat16* __restrict__ xlo,
    const __hip_bfloat16* __restrict__ wt,
    const float* __restrict__ bk, const float* __restrict__ bq,
    __hip_bfloat16* __restrict__ kout, __hip_bfloat16* __restrict__ qout) {

    __shared__ __align__(16) char AhiL[16384];
    __shared__ __align__(16) char AloL[16384];
    __shared__ __align__(16) char BL[8192];

    const int bid = blockIdx.x;                   // 768 = 8 x 96
    const int wg  = (bid & 7) * 96 + (bid >> 3);  // XCD chunk swizzle
    const int mt  = wg / 24;
    const int nc  = wg - mt * 24;
    const int wsel = nc / 12;
    const int nt  = nc - wsel * 12;
    const int m0 = mt * 128, n0 = nt * 64;

    const int tid = threadIdx.x;
    const int wv = tid >> 6;
    const int lane = tid & 63;
    const int lm = lane & 31, hi = lane >> 5;

    const __hip_bfloat16* wb = wt + (size_t)wsel * C_DIM * C_DIM;

    f32x16 acc0 = {}, acc1 = {};
    const int arow = wv * 32 + lm;
    const int asw = arow & 7;
    const int bsw = lm & 7;

    for (int k0 = 0; k0 < C_DIM; k0 += 64) {
        __syncthreads();   // previous iter's readers done before overwrite
#pragma unroll
        for (int it = 0; it < 4; ++it) {
            const int g = tid + it * 256;         // 0..1023
            const int row = g >> 3, ch = g & 7;
            const int dst = row * 128 + ((ch ^ (row & 7)) << 4);
            *reinterpret_cast<uint4*>(AhiL + dst) =
                *reinterpret_cast<const uint4*>(
                    xhi + (size_t)(m0 + row) * C_DIM + k0 + ch * 8);
            *reinterpret_cast<uint4*>(AloL + dst) =
                *reinterpret_cast<const uint4*>(
                    xlo + (size_t)(m0 + row) * C_DIM + k0 + ch * 8);
        }
#pragma unroll
        for (int it = 0; it < 2; ++it) {
            const int g = tid + it * 256;         // 0..511
            const int row = g >> 3, ch = g & 7;
            const int dst = row * 128 + ((ch ^ (row & 7)) << 4);
            *reinterpret_cast<uint4*>(BL + dst) =
                *reinterpret_cast<const uint4*>(
                    wb + (size_t)(n0 + row) * C_DIM + k0 + ch * 8);
        }
        __syncthreads();

#pragma unroll
        for (int ki = 0; ki < 4; ++ki) {
            const int ch = ki * 2 + hi;
            const bf16x8 ah = *reinterpret_cast<const bf16x8*>(
                AhiL + arow * 128 + ((ch ^ asw) << 4));
            const bf16x8 al = *reinterpret_cast<const bf16x8*>(
                AloL + arow * 128 + ((ch ^ asw) << 4));
            const bf16x8 b0 = *reinterpret_cast<const bf16x8*>(
                BL + lm * 128 + ((ch ^ bsw) << 4));
            const bf16x8 b1 = *reinterpret_cast<const bf16x8*>(
                BL + (32 + lm) * 128 + ((ch ^ bsw) << 4));
            acc0 = __builtin_amdgcn_mfma_f32_32x32x16_bf16(ah, b0, acc0, 0, 0, 0);
            acc1 = __builtin_amdgcn_mfma_f32_32x32x16_bf16(ah, b1, acc1, 0, 0, 0);
            acc0 = __builtin_amdgcn_mfma_f32_32x32x16_bf16(al, b0, acc0, 0, 0, 0);
            acc1 = __builtin_amdgcn_mfma_f32_32x32x16_bf16(al, b1, acc1, 0, 0, 0);
        }
    }

    const float* bias = wsel ? bq : bk;
    __hip_bfloat16* out = wsel ? qout : kout;
    const int h = nt;
    const float bv0 = bias[n0 + lm];
    const float bv1 = bias[n0 + 32 + lm];
#pragma unroll
    for (int r = 0; r < 16; ++r) {
        const int cr = (r & 3) + 8 * (r >> 2) + 4 * hi;
        const int t = m0 + wv * 32 + cr;
        out[((size_t)h * T_LEN + t) * D_DIM + lm]      = __float2bfloat16(acc0[r] + bv0);
        out[((size_t)h * T_LEN + t) * D_DIM + 32 + lm] = __float2bfloat16(acc1[r] + bv1);
    }
}

// ---------------------------------------------------------------------------
// Fallback prep + fp32 projection (round-3 validated) — only if ws is tiny.
// ---------------------------------------------------------------------------
__global__ __launch_bounds__(256) void vtx_only_kernel(
    const float* __restrict__ x, __hip_bfloat16* __restrict__ Vt) {
    __shared__ float tile[64][65];
    const int t0 = blockIdx.x * 64;
    const int c0 = blockIdx.y * 64;
    const int tid = threadIdx.x;
    const int cl = tid & 63;
    const int rq = tid >> 6;
#pragma unroll
    for (int rr = 0; rr < 16; ++rr) {
        const int row = rr * 4 + rq;
        tile[row][cl] = x[(size_t)(t0 + row) * C_DIM + c0 + cl];
    }
    __syncthreads();
#pragma unroll
    for (int cc = 0; cc < 16; ++cc) {
        const int c = cc * 4 + rq;
        const int gc = c0 + c;
        const int h = gc >> 6, d = gc & 63;
        Vt[((size_t)h * D_DIM + d) * T_LEN + t0 + cl] =
            __float2bfloat16(tile[cl][c]);
    }
}

__global__ __launch_bounds__(256) void proj_gemm(
    const float* __restrict__ x,
    const float* __restrict__ Wk, const float* __restrict__ bk,
    const float* __restrict__ Wq, const float* __restrict__ bq,
    __hip_bfloat16* __restrict__ kout, __hip_bfloat16* __restrict__ qout) {

    const float* W; const float* bias; __hip_bfloat16* out;
    if (blockIdx.z == 0) { W = Wk; bias = bk; out = kout; }
    else                 { W = Wq; bias = bq; out = qout; }

    __shared__ __align__(16) float As[32][68];
    __shared__ __align__(16) float Bs[32][68];

    const int tid = threadIdx.x;
    const int m0_blk = blockIdx.y * 64;
    const int n0_blk = blockIdx.x * 64;
    const int tx = tid & 15, ty = tid >> 4;
    const int mm = ty * 4, nn = tx * 4;
    float acc[4][4] = {};
    const int a_kq = tid & 7;
    const int a_m  = tid >> 3;
    const int b_n4 = (tid & 15) * 4;
    const int b_k  = tid >> 4;

    for (int k0 = 0; k0 < C_DIM; k0 += 32) {
#pragma unroll
        for (int half = 0; half < 2; ++half) {
            const int m = a_m + half * 32;
            const float4 av = *reinterpret_cast<const float4*>(
                &x[(size_t)(m0_blk + m) * C_DIM + k0 + a_kq * 4]);
            As[a_kq * 4 + 0][m] = av.x;
            As[a_kq * 4 + 1][m] = av.y;
            As[a_kq * 4 + 2][m] = av.z;
            As[a_kq * 4 + 3][m] = av.w;
        }
#pragma unroll
        for (int half = 0; half < 2; ++half) {
            const int kk = b_k + half * 16;
            *reinterpret_cast<float4*>(&Bs[kk][b_n4]) =
                *reinterpret_cast<const float4*>(
                    &W[(size_t)(k0 + kk) * C_DIM + n0_blk + b_n4]);
        }
        __syncthreads();
#pragma unroll
        for (int kk = 0; kk < 32; ++kk) {
            const float4 a4 = *reinterpret_cast<const float4*>(&As[kk][mm]);
            const float4 b4 = *reinterpret_cast<const float4*>(&Bs[kk][nn]);
            const float a_[4] = {a4.x, a4.y, a4.z, a4.w};
            const float b_[4] = {b4.x, b4.y, b4.z, b4.w};
#pragma unroll
            for (int i = 0; i < 4; ++i)
#pragma unroll
                for (int j = 0; j < 4; ++j)
                    acc[i][j] = fmaf(a_[i], b_[j], acc[i][j]);
        }
        __syncthreads();
    }

    const int h = blockIdx.x;
    const float4 bv = *reinterpret_cast<const float4*>(&bias[n0_blk + nn]);
    const float b_[4] = {bv.x, bv.y, bv.z, bv.w};
#pragma unroll
    for (int i = 0; i < 4; ++i) {
        const int t = m0_blk + mm + i;
        ushort4 o;
        o.x = bf16bits(acc[i][0] + b_[0]);
        o.y = bf16bits(acc[i][1] + b_[1]);
        o.z = bf16bits(acc[i][2] + b_[2]);
        o.w = bf16bits(acc[i][3] + b_[3]);
        *reinterpret_cast<ushort4*>(
            &out[((size_t)h * T_LEN + t) * D_DIM + nn]) = o;
    }
}

// ---------------------------------------------------------------------------
// LDS-staged split-j flash attention (validated round 10, 83 us).
// ---------------------------------------------------------------------------
template <typename TP>
__global__ __launch_bounds__(256) void attn_split2(
    const __hip_bfloat16* __restrict__ K,   // [H][T][64]
    const __hip_bfloat16* __restrict__ Q,   // [H][T][64]
    const __hip_bfloat16* __restrict__ Vt,  // [H][64][T]
    TP* __restrict__ pacc,                  // [3840][32*64]
    float* __restrict__ pml) {              // [3840][64]

    __shared__ __align__(16) char QsB[2][8192];
    __shared__ __align__(16) char VsB[2][8192];

    const int bid = blockIdx.x;                    // 960 = 8 x 120
    const int wg  = (bid & 7) * 120 + (bid >> 3);  // XCD chunk swizzle
    const int hh  = wg / 80;
    const int r   = 79 - (wg - hh * 80);           // heavy-first dispatch
    int ib, s;
    if (r < 8)       { ib = r; s = 0; }
    else if (r < 24) { const int q = r - 8;  ib = 8 + (q >> 1);  s = q & 1; }
    else if (r < 48) { const int q = r - 24; ib = 16 + q / 3;    s = q - 3 * (q / 3); }
    else             { const int q = r - 48; ib = 24 + (q >> 2); s = q & 3; }

    const int tid  = threadIdx.x;
    const int wv   = tid >> 6;
    const int lane = tid & 63;
    const int lm   = lane & 31;
    const int hi   = lane >> 5;
    const int t    = ib * 4 + wv;
    const int iw   = t * 32;

    const int jt0  = s * 32;
    const int jend = min((s + 1) * 32, ib * 4 + 4);
    const int nsteps = (jend - jt0) >> 1;

    const __hip_bfloat16* kp = K + ((size_t)hh * T_LEN + iw + lm) * D_DIM + hi * 8;
    const bf16x8 bk0 = *reinterpret_cast<const bf16x8*>(kp + 0);
    const bf16x8 bk1 = *reinterpret_cast<const bf16x8*>(kp + 16);
    const bf16x8 bk2 = *reinterpret_cast<const bf16x8*>(kp + 32);
    const bf16x8 bk3 = *reinterpret_cast<const bf16x8*>(kp + 48);

    const __hip_bfloat16* qsc = Q  + ((size_t)hh * T_LEN + jt0 * 32) * D_DIM;
    const __hip_bfloat16* vsc = Vt + (size_t)hh * D_DIM * T_LEN + jt0 * 32;

    const int k0c = tid, k1c = tid + 256;
    const int lo0 = (k0c >> 3) * 128 + (((k0c & 7) ^ ((k0c >> 3) & 7)) << 4);
    const int lo1 = (k1c >> 3) * 128 + (((k1c & 7) ^ ((k1c >> 3) & 7)) << 4);
    const size_t vro0 = (size_t)(tid >> 3) * T_LEN + (tid & 7) * 8;
    const size_t vro1 = (size_t)((tid >> 3) + 32) * T_LEN + (tid & 7) * 8;

    uint4 rq0 = *reinterpret_cast<const uint4*>(qsc + (size_t)k0c * 8);
    uint4 rq1 = *reinterpret_cast<const uint4*>(qsc + (size_t)k1c * 8);
    uint4 rv0 = *reinterpret_cast<const uint4*>(vsc + vro0);
    uint4 rv1 = *reinterpret_cast<const uint4*>(vsc + vro1);
    *reinterpret_cast<uint4*>(QsB[0] + lo0) = rq0;
    *reinterpret_cast<uint4*>(QsB[0] + lo1) = rq1;
    *reinterpret_cast<uint4*>(VsB[0] + lo0) = rv0;
    *reinterpret_cast<uint4*>(VsB[0] + lo1) = rv1;
    __syncthreads();

    f32x16 acc0 = {}, acc1 = {};
    float m = -1e30f, lsum = 0.0f;

#define COMPUTE(SUB) do {                                                     \
    const int jt_ = jt0 + st * 2 + (SUB);                                     \
    if (jt_ <= t) {                                                           \
        const char* qb = QsB[cur];                                            \
        const char* vb = VsB[cur];                                            \
        const int qrow = (SUB) * 32 + lm;                                     \
        const int qsw = qrow & 7;                                             \
        const bf16x8 aq0 = *reinterpret_cast<const bf16x8*>(                  \
            qb + qrow * 128 + (((0 + hi) ^ qsw) << 4));                       \
        const bf16x8 aq1 = *reinterpret_cast<const bf16x8*>(                  \
            qb + qrow * 128 + (((2 + hi) ^ qsw) << 4));                       \
        const bf16x8 aq2 = *reinterpret_cast<const bf16x8*>(                  \
            qb + qrow * 128 + (((4 + hi) ^ qsw) << 4));                       \
        const bf16x8 aq3 = *reinterpret_cast<const bf16x8*>(                  \
            qb + qrow * 128 + (((6 + hi) ^ qsw) << 4));                       \
        f32x16 sc = {};                                                       \
        sc = __builtin_amdgcn_mfma_f32_32x32x16_bf16(aq0, bk0, sc, 0, 0, 0);  \
        sc = __builtin_amdgcn_mfma_f32_32x32x16_bf16(aq1, bk1, sc, 0, 0, 0);  \
        sc = __builtin_amdgcn_mfma_f32_32x32x16_bf16(aq2, bk2, sc, 0, 0, 0);  \
        sc = __builtin_amdgcn_mfma_f32_32x32x16_bf16(aq3, bk3, sc, 0, 0, 0);  \
        if (jt_ == t) {                                                       \
            _Pragma("unroll")                                                 \
            for (int rr = 0; rr < 16; ++rr) {                                 \
                const int jr = (rr & 3) + 8 * (rr >> 2) + 4 * hi;             \
                if (jr > lm) sc[rr] = -1e30f;                                 \
            }                                                                 \
        }                                                                     \
        float pmax = sc[0];                                                   \
        _Pragma("unroll")                                                     \
        for (int rr = 1; rr < 16; ++rr) pmax = fmaxf(pmax, sc[rr]);           \
        pmax = fmaxf(pmax, __shfl_xor(pmax, 32));                             \
        if (__any(pmax > m + 8.0f)) {                                         \
            const float mn = fmaxf(m, pmax);                                  \
            const float scl = __expf(m - mn);                                 \
            lsum *= scl;                                                      \
            _Pragma("unroll")                                                 \
            for (int rr = 0; rr < 16; ++rr) {                                 \
                const float sr = __shfl(scl, (rr & 3) + 8 * (rr >> 2) + 4 * hi); \
                acc0[rr] *= sr;                                               \
                acc1[rr] *= sr;                                               \
            }                                                                 \
            m = mn;                                                           \
        }                                                                     \
        float p[16];                                                          \
        _Pragma("unroll")                                                     \
        for (int rr = 0; rr < 16; ++rr) p[rr] = __expf(sc[rr] - m);           \
        float ls = 0.0f;                                                      \
        _Pragma("unroll")                                                     \
        for (int rr = 0; rr < 16; ++rr) ls += p[rr];                          \
        lsum += ls;                                                           \
        unsigned int w_[8];                                                   \
        _Pragma("unroll")                                                     \
        for (int kk = 0; kk < 8; ++kk)                                        \
            w_[kk] = (unsigned int)bf16bits(p[2 * kk]) |                      \
                     ((unsigned int)bf16bits(p[2 * kk + 1]) << 16);           \
        unsigned int pw_[8];                                                  \
        _Pragma("unroll")                                                     \
        for (int kk = 0; kk < 8; ++kk) pw_[kk] = __shfl_xor((int)w_[kk], 32); \
        const uint4 a0u = hi ? make_uint4(pw_[2], pw_[3], w_[2], w_[3])       \
                             : make_uint4(w_[0], w_[1], pw_[0], pw_[1]);      \
        const uint4 a1u = hi ? make_uint4(pw_[6], pw_[7], w_[6], w_[7])       \
                             : make_uint4(w_[4], w_[5], pw_[4], pw_[5]);      \
        const bf16x8 pa0 = __builtin_bit_cast(bf16x8, a0u);                   \
        const bf16x8 pa1 = __builtin_bit_cast(bf16x8, a1u);                   \
        const int d0 = lm, d1 = 32 + lm;                                      \
        const int vsw = lm & 7;                                               \
        const bf16x8 v00 = *reinterpret_cast<const bf16x8*>(                  \
            vb + d0 * 128 + ((((SUB) * 4 + 0 + hi) ^ vsw) << 4));             \
        const bf16x8 v01 = *reinterpret_cast<const bf16x8*>(                  \
            vb + d0 * 128 + ((((SUB) * 4 + 2 + hi) ^ vsw) << 4));             \
        const bf16x8 v10 = *reinterpret_cast<const bf16x8*>(                  \
            vb + d1 * 128 + ((((SUB) * 4 + 0 + hi) ^ vsw) << 4));             \
        const bf16x8 v11 = *reinterpret_cast<const bf16x8*>(                  \
            vb + d1 * 128 + ((((SUB) * 4 + 2 + hi) ^ vsw) << 4));             \
        acc0 = __builtin_amdgcn_mfma_f32_32x32x16_bf16(pa0, v00, acc0, 0,0,0);\
        acc0 = __builtin_amdgcn_mfma_f32_32x32x16_bf16(pa1, v01, acc0, 0,0,0);\
        acc1 = __builtin_amdgcn_mfma_f32_32x32x16_bf16(pa0, v10, acc1, 0,0,0);\
        acc1 = __builtin_amdgcn_mfma_f32_32x32x16_bf16(pa1, v11, acc1, 0,0,0);\
    }                                                                         \
} while (0)

    int cur = 0;
    for (int st = 0; st < nsteps; ++st) {
        const bool more = (st + 1 < nsteps);
        if (more) {
            rq0 = *reinterpret_cast<const uint4*>(qsc + (size_t)(st + 1) * 4096 + (size_t)k0c * 8);
            rq1 = *reinterpret_cast<const uint4*>(qsc + (size_t)(st + 1) * 4096 + (size_t)k1c * 8);
            rv0 = *reinterpret_cast<const uint4*>(vsc + vro0 + (size_t)(st + 1) * 64);
            rv1 = *reinterpret_cast<const uint4*>(vsc + vro1 + (size_t)(st + 1) * 64);
        }
        COMPUTE(0);
        COMPUTE(1);
        if (more) {
            char* qn = QsB[cur ^ 1];
            char* vn = VsB[cur ^ 1];
            *reinterpret_cast<uint4*>(qn + lo0) = rq0;
            *reinterpret_cast<uint4*>(qn + lo1) = rq1;
            *reinterpret_cast<uint4*>(vn + lo0) = rv0;
            *reinterpret_cast<uint4*>(vn + lo1) = rv1;
        }
        __syncthreads();
        cur ^= 1;
    }
#undef COMPUTE

    const int slot = (hh * 80 + r) * 4 + wv;
    const float lrow = lsum + __shfl_xor(lsum, 32);
    if (hi == 0) {
        pml[(size_t)slot * 64 + lm]      = m;
        pml[(size_t)slot * 64 + 32 + lm] = lrow;
    }
    TP* pa = pacc + (size_t)slot * 2048;
#pragma unroll
    for (int rr = 0; rr < 16; ++rr) {
        const int cr = (rr & 3) + 8 * (rr >> 2) + 4 * hi;
        stp(&pa[cr * 64 + lm],      acc0[rr]);
        stp(&pa[cr * 64 + 32 + lm], acc1[rr]);
    }
}

// ---------------------------------------------------------------------------
// Merge partials (validated round 10): slot = (h*80 + bb + s)*4 + w.
// ---------------------------------------------------------------------------
template <typename TP>
__global__ __launch_bounds__(256) void attn_merge(
    const TP* __restrict__ pacc, const float* __restrict__ pml,
    float* __restrict__ y) {
    const int b = blockIdx.x;          // 1536
    const int h = b / 128;
    const int t = b - h * 128;
    const int ib = t >> 2, w = t & 3;
    const int ns = (t >> 5) + 1;
    int bb;
    if (ib < 8)       bb = ib;
    else if (ib < 16) bb = 8 + (ib - 8) * 2;
    else if (ib < 24) bb = 24 + (ib - 16) * 3;
    else              bb = 48 + (ib - 24) * 4;
    const int slot0 = (h * 80 + bb) * 4 + w;
    const int tid = threadIdx.x;
    const int row = tid >> 3;
    const int dq  = (tid & 7) * 8;

    float m0 = pml[(size_t)slot0 * 64 + row];
    float l0 = pml[(size_t)slot0 * 64 + 32 + row];
    float m1 = -1e30f, l1 = 0.f, m2 = -1e30f, l2 = 0.f, m3 = -1e30f, l3 = 0.f;
    if (ns > 1) { m1 = pml[(size_t)(slot0 + 4) * 64 + row];  l1 = pml[(size_t)(slot0 + 4) * 64 + 32 + row]; }
    if (ns > 2) { m2 = pml[(size_t)(slot0 + 8) * 64 + row];  l2 = pml[(size_t)(slot0 + 8) * 64 + 32 + row]; }
    if (ns > 3) { m3 = pml[(size_t)(slot0 + 12) * 64 + row]; l3 = pml[(size_t)(slot0 + 12) * 64 + 32 + row]; }
    const float M = fmaxf(fmaxf(m0, m1), fmaxf(m2, m3));
    const float w0 = __expf(m0 - M), w1 = __expf(m1 - M);
    const float w2 = __expf(m2 - M), w3 = __expf(m3 - M);
    const float L = l0 * w0 + l1 * w1 + l2 * w2 + l3 * w3;
    const float inv = 1.0f / L;

    float o[8] = {};
    {
        const TP* pa = pacc + (size_t)slot0 * 2048 + row * 64 + dq;
#pragma unroll
        for (int k = 0; k < 8; ++k) o[k] += ldp(&pa[k]) * w0;
    }
    if (ns > 1) {
        const TP* pa = pacc + (size_t)(slot0 + 4) * 2048 + row * 64 + dq;
#pragma unroll
        for (int k = 0; k < 8; ++k) o[k] += ldp(&pa[k]) * w1;
    }
    if (ns > 2) {
        const TP* pa = pacc + (size_t)(slot0 + 8) * 2048 + row * 64 + dq;
#pragma unroll
        for (int k = 0; k < 8; ++k) o[k] += ldp(&pa[k]) * w2;
    }
    if (ns > 3) {
        const TP* pa = pacc + (size_t)(slot0 + 12) * 2048 + row * 64 + dq;
#pragma unroll
        for (int k = 0; k < 8; ++k) o[k] += ldp(&pa[k]) * w3;
    }
    float* yp = &y[(size_t)(t * 32 + row) * C_DIM + h * D_DIM + dq];
    float4 o0, o1;
    o0.x = o[0] * inv; o0.y = o[1] * inv; o0.z = o[2] * inv; o0.w = o[3] * inv;
    o1.x = o[4] * inv; o1.y = o[5] * inv; o1.z = o[6] * inv; o1.w = o[7] * inv;
    *reinterpret_cast<float4*>(yp + 0) = o0;
    *reinterpret_cast<float4*>(yp + 4) = o1;
}

// ---------------------------------------------------------------------------
// Flat attention fallback (round-3 validated): wave per (h, itile).
// ---------------------------------------------------------------------------
__global__ __launch_bounds__(256) void attn_flat(
    const __hip_bfloat16* __restrict__ K,
    const __hip_bfloat16* __restrict__ Q,
    const __hip_bfloat16* __restrict__ Vt,
    float* __restrict__ y) {

    const int u  = blockIdx.x * 4 + (threadIdx.x >> 6);
    const int h  = u % H_NUM;
    const int itile = (T_LEN / 32 - 1) - u / H_NUM;
    const int iw = itile * 32;
    const int lane = threadIdx.x & 63;
    const int lm = lane & 31;
    const int hi = lane >> 5;

    const __hip_bfloat16* kp = K + ((size_t)h * T_LEN + iw + lm) * D_DIM + hi * 8;
    const bf16x8 bk0 = *reinterpret_cast<const bf16x8*>(kp + 0);
    const bf16x8 bk1 = *reinterpret_cast<const bf16x8*>(kp + 16);
    const bf16x8 bk2 = *reinterpret_cast<const bf16x8*>(kp + 32);
    const bf16x8 bk3 = *reinterpret_cast<const bf16x8*>(kp + 48);

    f32x16 acc0 = {}, acc1 = {};
    float m = -1e30f, lsum = 0.0f;

    const __hip_bfloat16* qrow  = Q  + ((size_t)h * T_LEN + lm) * D_DIM + hi * 8;
    const __hip_bfloat16* vrow0 = Vt + ((size_t)h * D_DIM + lm) * T_LEN + hi * 8;
    const __hip_bfloat16* vrow1 = vrow0 + (size_t)32 * T_LEN;

    for (int j0 = 0; j0 <= iw; j0 += 32) {
        const __hip_bfloat16* qp = qrow + (size_t)j0 * D_DIM;
        const bf16x8 aq0 = *reinterpret_cast<const bf16x8*>(qp + 0);
        const bf16x8 aq1 = *reinterpret_cast<const bf16x8*>(qp + 16);
        const bf16x8 aq2 = *reinterpret_cast<const bf16x8*>(qp + 32);
        const bf16x8 aq3 = *reinterpret_cast<const bf16x8*>(qp + 48);

        f32x16 sc = {};
        sc = __builtin_amdgcn_mfma_f32_32x32x16_bf16(aq0, bk0, sc, 0, 0, 0);
        sc = __builtin_amdgcn_mfma_f32_32x32x16_bf16(aq1, bk1, sc, 0, 0, 0);
        sc = __builtin_amdgcn_mfma_f32_32x32x16_bf16(aq2, bk2, sc, 0, 0, 0);
        sc = __builtin_amdgcn_mfma_f32_32x32x16_bf16(aq3, bk3, sc, 0, 0, 0);

        if (j0 == iw) {
#pragma unroll
            for (int r = 0; r < 16; ++r) {
                const int jr = (r & 3) + 8 * (r >> 2) + 4 * hi;
                if (jr > lm) sc[r] = -1e30f;
            }
        }

        float pmax = sc[0];
#pragma unroll
        for (int r = 1; r < 16; ++r) pmax = fmaxf(pmax, sc[r]);
        pmax = fmaxf(pmax, __shfl_xor(pmax, 32));

        if (__any(pmax > m + 8.0f)) {
            const float mn = fmaxf(m, pmax);
            const float scl = __expf(m - mn);
            lsum *= scl;
#pragma unroll
            for (int r = 0; r < 16; ++r) {
                const float sr = __shfl(scl, (r & 3) + 8 * (r >> 2) + 4 * hi);
                acc0[r] *= sr;
                acc1[r] *= sr;
            }
            m = mn;
        }

        float p[16];
#pragma unroll
        for (int r = 0; r < 16; ++r) p[r] = __expf(sc[r] - m);
        float ls = 0.0f;
#pragma unroll
        for (int r = 0; r < 16; ++r) ls += p[r];
        lsum += ls;

        unsigned int w[8];
#pragma unroll
        for (int k = 0; k < 8; ++k)
            w[k] = (unsigned int)bf16bits(p[2 * k]) |
                   ((unsigned int)bf16bits(p[2 * k + 1]) << 16);
        unsigned int pw[8];
#pragma unroll
        for (int k = 0; k < 8; ++k) pw[k] = __shfl_xor((int)w[k], 32);

        const uint4 a0u = hi ? make_uint4(pw[2], pw[3], w[2], w[3])
                             : make_uint4(w[0], w[1], pw[0], pw[1]);
        const uint4 a1u = hi ? make_uint4(pw[6], pw[7], w[6], w[7])
                             : make_uint4(w[4], w[5], pw[4], pw[5]);
        const bf16x8 pa0 = __builtin_bit_cast(bf16x8, a0u);
        const bf16x8 pa1 = __builtin_bit_cast(bf16x8, a1u);

        const bf16x8 v00 = *reinterpret_cast<const bf16x8*>(vrow0 + j0);
        const bf16x8 v01 = *reinterpret_cast<const bf16x8*>(vrow0 + j0 + 16);
        const bf16x8 v10 = *reinterpret_cast<const bf16x8*>(vrow1 + j0);
        const bf16x8 v11 = *reinterpret_cast<const bf16x8*>(vrow1 + j0 + 16);

        acc0 = __builtin_amdgcn_mfma_f32_32x32x16_bf16(pa0, v00, acc0, 0, 0, 0);
        acc0 = __builtin_amdgcn_mfma_f32_32x32x16_bf16(pa1, v01, acc0, 0, 0, 0);
        acc1 = __builtin_amdgcn_mfma_f32_32x32x16_bf16(pa0, v10, acc1, 0, 0, 0);
        acc1 = __builtin_amdgcn_mfma_f32_32x32x16_bf16(pa1, v11, acc1, 0, 0, 0);
    }

    const float lt = lsum + __shfl_xor(lsum, 32);
    const float linv = 1.0f / lt;
#pragma unroll
    for (int r = 0; r < 16; ++r) {
        const int cr = (r & 3) + 8 * (r >> 2) + 4 * hi;
        const int row = iw + cr;
        const float li = __shfl(linv, cr);
        y[(size_t)row * C_DIM + h * D_DIM + lm]      = acc0[r] * li;
        y[(size_t)row * C_DIM + h * D_DIM + 32 + lm] = acc1[r] * li;
    }
}

// ---------------------------------------------------------------------------
extern "C" void kernel_launch(void* const* d_in, const int* in_sizes, int n_in,
                              void* d_out, int out_size, void* d_ws, size_t ws_size,
                              hipStream_t stream) {
    const float* x  = (const float*)d_in[0];
    const float* Wk = (const float*)d_in[1];
    const float* bk = (const float*)d_in[2];
    const float* Wq = (const float*)d_in[3];
    const float* bq = (const float*)d_in[4];
    float* out = (float*)d_out;

    const size_t np = (size_t)T_LEN * C_DIM;           // 3,145,728
    const size_t NSLOT = 3840;
    __hip_bfloat16* kbuf  = (__hip_bfloat16*)d_ws;     // [H][T][64]
    __hip_bfloat16* qbuf  = kbuf + np;                 // [H][T][64]
    __hip_bfloat16* vtbuf = qbuf + np;                 // [H][64][T]
    char* after_kqv = (char*)(vtbuf + np);
    __hip_bfloat16* wtbuf = (__hip_bfloat16*)after_kqv;  // dead after proj

    const size_t wt_bytes   = 2 * (size_t)C_DIM * C_DIM * sizeof(__hip_bfloat16);
    const size_t pacc_f32_b = NSLOT * 2048 * sizeof(float);
    const size_t pacc_b16_b = NSLOT * 2048 * sizeof(__hip_bfloat16);
    const size_t pml_b      = NSLOT * 64 * sizeof(float);
    const size_t base_b     = 3 * np * sizeof(__hip_bfloat16);
    const size_t needC = base_b + wt_bytes;                 // ~21.2 MB
    const size_t needB = base_b + pacc_b16_b + pml_b;       // ~35.6 MB
    const size_t needA = base_b + pacc_f32_b + pml_b;       // ~51.3 MB

    __hip_bfloat16* xhi = (__hip_bfloat16*)d_out;      // overlay d_out
    __hip_bfloat16* xlo = xhi + np;

    if (ws_size >= needC) {
        prep_kernel<<<1056, 256, 0, stream>>>(x, Wk, Wq, vtbuf, xhi, xlo, wtbuf);
        proj_mfma2<<<768, 256, 0, stream>>>(xhi, xlo, wtbuf, bk, bq, kbuf, qbuf);
    } else {
        dim3 gv(T_LEN / 64, C_DIM / 64);
        vtx_only_kernel<<<gv, 256, 0, stream>>>(x, vtbuf);
        dim3 g1(C_DIM / 64, T_LEN / 64, 2);
        proj_gemm<<<g1, 256, 0, stream>>>(x, Wk, bk, Wq, bq, kbuf, qbuf);
    }

    if (ws_size >= needA) {
        float* pacc = (float*)after_kqv;
        float* pml  = (float*)(after_kqv + pacc_f32_b);
        attn_split2<float><<<960, 256, 0, stream>>>(kbuf, qbuf, vtbuf, pacc, pml);
        attn_merge<float><<<1536, 256, 0, stream>>>(pacc, pml, out);
    } else if (ws_size >= needB) {
        __hip_bfloat16* pacc = (__hip_bfloat16*)after_kqv;
        float* pml = (float*)(after_kqv + pacc_b16_b);
        attn_split2<__hip_bfloat16><<<960, 256, 0, stream>>>(kbuf, qbuf, vtbuf, pacc, pml);
        attn_merge<__hip_bfloat16><<<1536, 256, 0, stream>>>(pacc, pml, out);
    } else {
        attn_flat<<<384, 256, 0, stream>>>(kbuf, qbuf, vtbuf, out);
    }
}